// Round 12
// baseline (978.414 us; speedup 1.0000x reference)
//
#include <hip/hip_runtime.h>
#include <hip/hip_bf16.h>

// SCAM fused kernel for MI355X (gfx950).
// R12 = R11 (V-in-registers, K=16 PV, swizzled LDS) restructured as a
// persistent kernel: 256 WGs x 6 slices (same batch). Slice i+1's x is
// prefetched into the (dead after phase 4) xl/xr LDS buffers DURING slice
// i's attention phases, via two 24-VGPR register windows each spanning ONE
// phase (issue after B4 / write after B5 for x_l; issue after B5 / write
// after B6 for x_r). Epilogue re-reads x from global (L3-hot, R8-proven)
// since xl/xr hold next slice's data by then. Removes 5 of 6 exposed
// staging phases + per-slice misc setup.

typedef __attribute__((ext_vector_type(8))) short bhalf8;   // 8 bf16 (K=32 frag)
typedef __attribute__((ext_vector_type(4))) short bhalf4;   // 4 bf16 (K=16 frag)
typedef __attribute__((ext_vector_type(4))) float f32x4;

#define DEVI static __device__ __forceinline__

constexpr int Cc   = 192;
constexpr int HWc  = 9216;          // 96*96
constexpr int CHW  = 192 * 9216;    // per-batch image
constexpr int HALF_OUT = 16 * CHW;  // 28311552
constexpr int PPS  = 100;           // P row stride (halves)
constexpr int AS   = 100;           // att row stride (dwords)

DEVI unsigned short f2bf(float f) {           // hw cvt (RNE) via hip_bf16
  __hip_bfloat16 h = __float2bfloat16(f);
  return __builtin_bit_cast(unsigned short, h);
}
DEVI unsigned pk2bf(float a, float b) {       // packed pair: a -> low, b -> high
  return (unsigned)f2bf(a) | ((unsigned)f2bf(b) << 16);
}
DEVI float bf2f(unsigned short h) {
  unsigned u = (unsigned)h << 16;
  return __builtin_bit_cast(float, u);
}
DEVI float bf2f_s(short h) { return bf2f((unsigned short)h); }

// ---------------------------------------------------------------- setup 1 ---
__global__ void setup1(
    const float* __restrict__ t,
    const float* __restrict__ lnwl, const float* __restrict__ lnbl,
    const float* __restrict__ lnwr, const float* __restrict__ lnbr,
    const float* __restrict__ Wl1, const float* __restrict__ bl1,
    const float* __restrict__ Wr1, const float* __restrict__ br1,
    const float* __restrict__ Wl2, const float* __restrict__ Wr2,
    short* __restrict__ W1l_b, short* __restrict__ W1r_b,
    short* __restrict__ W2l_b, short* __restrict__ W2r_b,
    float* __restrict__ s1l, float* __restrict__ t1l,
    float* __restrict__ s1r, float* __restrict__ t1r,
    float* __restrict__ mt)
{
  const int blk = blockIdx.x, tid = threadIdx.x;
  if (blk < 576) {
    int id  = blk * 256 + tid;          // < 147456
    int m   = id / 36864;
    int rem = id - m * 36864;
    int c   = rem % 192;
    float v;
    short* dst;
    if (m == 0)      { v = lnwl[c] * Wl1[rem]; dst = W1l_b; }
    else if (m == 1) { v = lnwr[c] * Wr1[rem]; dst = W1r_b; }
    else if (m == 2) { v = Wl2[rem];           dst = W2l_b; }
    else             { v = Wr2[rem];           dst = W2r_b; }
    dst[rem] = (short)f2bf(v);
  } else if (blk == 576 || blk == 577) {
    if (tid < 192) {
      const float* Wm = (blk == 576) ? Wl1 : Wr1;
      const float* lw = (blk == 576) ? lnwl : lnwr;
      const float* lb = (blk == 576) ? lnbl : lnbr;
      const float* bb = (blk == 576) ? bl1 : br1;
      float s = 0.f, tb = 0.f;
      for (int c = 0; c < 192; ++c) {
        float wv = Wm[tid * 192 + c];
        s  += lw[c] * wv;
        tb += lb[c] * wv;
      }
      if (blk == 576) { s1l[tid] = s; t1l[tid] = tb + bb[tid]; }
      else            { s1r[tid] = s; t1r[tid] = tb + bb[tid]; }
    }
  } else {
    int id = (blk - 578) * 256 + tid;   // < 8192
    float v = t[id];
    float sp = (v > 20.f) ? v : log1pf(__expf(v));
    mt[id] = v * tanhf(sp);
  }
}

// temb[b][o] = sum_k mish(t)[b][k] * Wt[o][k] + bt[o]
__global__ void setup2(const float* __restrict__ mt, const float* __restrict__ Wt,
                       const float* __restrict__ bt, float* __restrict__ temb)
{
  int id = blockIdx.x * 256 + threadIdx.x;  // < 3072
  int b = id / 192, o = id - b * 192;
  float s = 0.f;
  for (int k = 0; k < 512; ++k) s += mt[b * 512 + k] * Wt[o * 512 + k];
  temb[id] = s + bt[o];
}

// ------------------------------------------------------------- main kernel ---
// misc layout (floats): 0 mu_l[96], 96 rs_l[96], 192 mu_r[96], 288 rs_r[96],
// 384 te[192], 576 beta[192], 768 gamma[192]   (end 960)
struct SmemT {
  short xl[19200];   // X_l bf16 swizzled [w][c] stride 200 (dead after P4 -> prefetch target)
  short xr[19200];   // X_r
  short q1[19200];   // Q_l -> att (fp32 96x100dw) -> F_r2l
  short q2[19200];   // Q_r -> P_row/P_colT (stride 100) -> F_l2r
  float misc[960];
};
static_assert(sizeof(SmemT) <= 163840, "LDS overflow");

__launch_bounds__(768, 3)
__global__ void scam_main(
    const float* __restrict__ x_l, const float* __restrict__ x_r,
    const float* __restrict__ bl2, const float* __restrict__ br2,
    const float* __restrict__ beta, const float* __restrict__ gamma,
    const short* __restrict__ W1l_b, const short* __restrict__ W1r_b,
    const short* __restrict__ W2l_b, const short* __restrict__ W2r_b,
    const float* __restrict__ s1l, const float* __restrict__ t1l,
    const float* __restrict__ s1r, const float* __restrict__ t1r,
    const float* __restrict__ temb,
    float* __restrict__ out)
{
  __shared__ SmemT sm;
  const int tid  = threadIdx.x;
  const int lane = tid & 63;
  const int wid  = tid >> 6;            // 0..11
  const int m16  = lane & 15;
  const int hb   = lane >> 4;           // 0..3
  const int kc8  = hb * 8;              // K=32 fragment element offset
  const int r4   = hb * 4;              // D-row base
  const int wg   = blockIdx.x;          // 0..255 persistent WGs
  const int bb_  = wg >> 4;             // batch (16 WGs/batch; 96 = 16*6)
  const int hh0  = 6 * (wg & 15);
  const int baseB = bb_ * CHW;
  const int o_wm = wid * 16 + m16;

  // thread -> (c, w4) staging/epilogue map components (reused everywhere)
  // i4 = j*768 + tid ; c = i4/24 ; w4 = i4%24

  // prologue: misc (b constant across this WG's 6 slices) + stage slice 0
  if (tid < 576) {
    int a = tid / 192, o = tid - a * 192;
    if (a == 0)      sm.misc[384 + o] = temb[bb_ * 192 + o];
    else if (a == 1) sm.misc[576 + o] = beta[o];
    else             sm.misc[768 + o] = gamma[o];
  }
  {
    const int sb = baseB + hh0 * 96;
    #pragma unroll
    for (int j = 0; j < 6; ++j) {
      int i4 = j * 768 + tid;
      int c  = i4 / 24;
      int w4 = i4 - c * 24;
      const float4 xl4 = *reinterpret_cast<const float4*>(x_l + sb + c * HWc + w4 * 4);
      const float4 xr4 = *reinterpret_cast<const float4*>(x_r + sb + c * HWc + w4 * 4);
      int sw = ((((c >> 3) ^ (w4 & 7)) << 3) | (c & 7));
      int base = w4 * 800 + sw;
      sm.xl[base      ] = (short)f2bf(xl4.x);
      sm.xl[base + 200] = (short)f2bf(xl4.y);
      sm.xl[base + 400] = (short)f2bf(xl4.z);
      sm.xl[base + 600] = (short)f2bf(xl4.w);
      sm.xr[base      ] = (short)f2bf(xr4.x);
      sm.xr[base + 200] = (short)f2bf(xr4.y);
      sm.xr[base + 400] = (short)f2bf(xr4.z);
      sm.xr[base + 600] = (short)f2bf(xr4.w);
    }
  }
  __syncthreads();                                   // B1

  #pragma unroll 1
  for (int it = 0; it < 6; ++it) {
    const int sliceBase = baseB + (hh0 + it) * 96;
    float4 xsl[6], xsr[6];                           // 1-phase prefetch windows

    // phase 2: LN stats per pixel
    {
      int side = (tid >= 384) ? 1 : 0;
      int rest = tid - side * 384;
      int w = rest >> 2;
      int q = rest & 3;
      const short* Xb = side ? sm.xr : sm.xl;
      const int kxw = (w >> 2) & 7;
      float s0 = 0.f, s2 = 0.f;
      #pragma unroll
      for (int mc = 0; mc < 6; ++mc) {
        bhalf8 v = *reinterpret_cast<const bhalf8*>(Xb + w * 200 + (((q * 6 + mc) ^ kxw) << 3));
        #pragma unroll
        for (int e = 0; e < 8; ++e) { float f = bf2f_s(v[e]); s0 += f; s2 += f * f; }
      }
      s0 += __shfl_xor(s0, 1); s2 += __shfl_xor(s2, 1);
      s0 += __shfl_xor(s0, 2); s2 += __shfl_xor(s2, 2);
      if (q == 0) {
        float mu  = s0 * (1.f / 192.f);
        float var = s2 * (1.f / 192.f) - mu * mu;
        float rs  = rsqrtf(var + 1e-6f);
        sm.misc[side * 192 + w]      = mu;
        sm.misc[side * 192 + 96 + w] = rs;
      }
    }

    // phase 3: V^T fragments into registers. D[m=x][n=c]: lane holds
    // V^T[c=o_wm][y=xi*16+hb*4+j] — the K=16 PV A-fragment for k-tile xi.
    uint2 vRl[6], vRr[6];
    #pragma unroll
    for (int sd = 0; sd < 2; ++sd) {
      const short* Wb = sd ? W2r_b : W2l_b;
      const short* Xb = sd ? sm.xr : sm.xl;
      const float bv = (sd ? br2 : bl2)[o_wm];
      bhalf8 af[6];
      #pragma unroll
      for (int k = 0; k < 6; ++k)
        af[k] = *reinterpret_cast<const bhalf8*>(Wb + o_wm * 192 + k * 32 + kc8);
      #pragma unroll
      for (int xi = 0; xi < 6; ++xi) {
        const int row = xi * 16 + m16;
        const int kxr = (row >> 2) & 7;
        const short* Xr = Xb + row * 200;
        f32x4 acc = {0.f, 0.f, 0.f, 0.f};
        #pragma unroll
        for (int k = 0; k < 6; ++k) {
          bhalf8 bfr = *reinterpret_cast<const bhalf8*>(Xr + (((k * 4 + hb) ^ kxr) << 3));
          acc = __builtin_amdgcn_mfma_f32_16x16x32_bf16(bfr, af[k], acc, 0, 0, 0);
        }
        uint2 pv;
        pv.x = pk2bf(acc[0] + bv, acc[1] + bv);
        pv.y = pk2bf(acc[2] + bv, acc[3] + bv);
        if (sd) vRr[xi] = pv; else vRl[xi] = pv;
      }
    }

    // phase 4A: Q_l accs (reads X_l), D[m=o][n=x]
    f32x4 accQ[6];
    {
      bhalf8 bfq[6];
      #pragma unroll
      for (int k = 0; k < 6; ++k)
        bfq[k] = *reinterpret_cast<const bhalf8*>(W1l_b + o_wm * 192 + k * 32 + kc8);
      #pragma unroll
      for (int mi = 0; mi < 6; ++mi) {
        const int row = mi * 16 + m16;
        const int kxr = (row >> 2) & 7;
        const short* Xr = sm.xl + row * 200;
        f32x4 acc = {0.f, 0.f, 0.f, 0.f};
        #pragma unroll
        for (int k = 0; k < 6; ++k) {
          bhalf8 afr = *reinterpret_cast<const bhalf8*>(Xr + (((k * 4 + hb) ^ kxr) << 3));
          acc = __builtin_amdgcn_mfma_f32_16x16x32_bf16(bfq[k], afr, acc, 0, 0, 0);
        }
        accQ[mi] = acc;
      }
    }
    __syncthreads();                                 // B2 (LN misc ready)
    // write Q_l -> q1: Q = rs*acc - mu*rs*s1 + t1
    {
      const int obase = wid * 16 + r4;
      const int oblk  = obase >> 3;
      const int osub  = (hb & 1) * 4;
      const float* muA = sm.misc;
      const float* rsA = sm.misc + 96;
      float s1v[4], t1v[4];
      #pragma unroll
      for (int j = 0; j < 4; ++j) { s1v[j] = s1l[obase + j]; t1v[j] = t1l[obase + j]; }
      #pragma unroll
      for (int mi = 0; mi < 6; ++mi) {
        const int x = mi * 16 + m16;
        const int kx = (x >> 2) & 7;
        float mu = muA[x], rs = rsA[x];
        float mrs = mu * rs;
        f32x4 acc = accQ[mi];
        uint2 pv;
        pv.x = pk2bf(rs * acc[0] - mrs * s1v[0] + t1v[0],
                     rs * acc[1] - mrs * s1v[1] + t1v[1]);
        pv.y = pk2bf(rs * acc[2] - mrs * s1v[2] + t1v[2],
                     rs * acc[3] - mrs * s1v[3] + t1v[3]);
        *reinterpret_cast<uint2*>(sm.q1 + x * 200 + (((oblk ^ kx) << 3) | osub)) = pv;
      }
    }
    // phase 4B: Q_r accs (reads X_r) then write -> q2
    {
      bhalf8 bfq[6];
      #pragma unroll
      for (int k = 0; k < 6; ++k)
        bfq[k] = *reinterpret_cast<const bhalf8*>(W1r_b + o_wm * 192 + k * 32 + kc8);
      #pragma unroll
      for (int mi = 0; mi < 6; ++mi) {
        const int row = mi * 16 + m16;
        const int kxr = (row >> 2) & 7;
        const short* Xr = sm.xr + row * 200;
        f32x4 acc = {0.f, 0.f, 0.f, 0.f};
        #pragma unroll
        for (int k = 0; k < 6; ++k) {
          bhalf8 afr = *reinterpret_cast<const bhalf8*>(Xr + (((k * 4 + hb) ^ kxr) << 3));
          acc = __builtin_amdgcn_mfma_f32_16x16x32_bf16(bfq[k], afr, acc, 0, 0, 0);
        }
        accQ[mi] = acc;
      }
    }
    {
      const int obase = wid * 16 + r4;
      const int oblk  = obase >> 3;
      const int osub  = (hb & 1) * 4;
      const float* muA = sm.misc + 192;
      const float* rsA = sm.misc + 288;
      float s1v[4], t1v[4];
      #pragma unroll
      for (int j = 0; j < 4; ++j) { s1v[j] = s1r[obase + j]; t1v[j] = t1r[obase + j]; }
      #pragma unroll
      for (int mi = 0; mi < 6; ++mi) {
        const int x = mi * 16 + m16;
        const int kx = (x >> 2) & 7;
        float mu = muA[x], rs = rsA[x];
        float mrs = mu * rs;
        f32x4 acc = accQ[mi];
        uint2 pv;
        pv.x = pk2bf(rs * acc[0] - mrs * s1v[0] + t1v[0],
                     rs * acc[1] - mrs * s1v[1] + t1v[1]);
        pv.y = pk2bf(rs * acc[2] - mrs * s1v[2] + t1v[2],
                     rs * acc[3] - mrs * s1v[3] + t1v[3]);
        *reinterpret_cast<uint2*>(sm.q2 + x * 200 + (((oblk ^ kx) << 3) | osub)) = pv;
      }
    }
    __syncthreads();                                 // B3  (X now dead)

    // phase 5: att = Q_l * Q_r^T (scaled) -> fp32 over q1, swizzle y^(x&31)
    {
      const int mi = wid >> 1;
      const int yb = (wid & 1) * 3;
      const int arow = mi * 16 + m16;
      const int kxa = (arow >> 2) & 7;
      bhalf8 afa[6];
      #pragma unroll
      for (int k = 0; k < 6; ++k)
        afa[k] = *reinterpret_cast<const bhalf8*>(sm.q1 + arow * 200 + (((k * 4 + hb) ^ kxa) << 3));
      f32x4 accA[3];
      #pragma unroll
      for (int yt = 0; yt < 3; ++yt) {
        const int brow = (yb + yt) * 16 + m16;
        const int kxb = (brow >> 2) & 7;
        const short* Br = sm.q2 + brow * 200;
        f32x4 acc = {0.f, 0.f, 0.f, 0.f};
        #pragma unroll
        for (int k = 0; k < 6; ++k) {
          bhalf8 bfy = *reinterpret_cast<const bhalf8*>(Br + (((k * 4 + hb) ^ kxb) << 3));
          acc = __builtin_amdgcn_mfma_f32_16x16x32_bf16(afa[k], bfy, acc, 0, 0, 0);
        }
        accA[yt] = acc;
      }
      __syncthreads();                               // B4i (internal)
      float* attf = reinterpret_cast<float*>(sm.q1);
      const float scale = 0.07216878364870323f;      // 192^-0.5
      #pragma unroll
      for (int yt = 0; yt < 3; ++yt) {
        #pragma unroll
        for (int j = 0; j < 4; ++j) {
          int x = mi * 16 + r4 + j;
          int y = (yb + yt) * 16 + m16;
          attf[x * AS + (y ^ (x & 31))] = accA[yt][j] * scale;
        }
      }
    }
    __syncthreads();                                 // B4

    // W1 issue: prefetch next slice's x_l (in flight across softmax)
    if (it < 5) {
      const int sbn = sliceBase + 96;
      #pragma unroll
      for (int j = 0; j < 6; ++j) {
        int i4 = j * 768 + tid;
        int c  = i4 / 24;
        int w4 = i4 - c * 24;
        xsl[j] = *reinterpret_cast<const float4*>(x_l + sbn + c * HWc + w4 * 4);
      }
    }

    // phase 6: dual softmax -> P_row / P_colT (bf16, stride 100) in q2
    {
      const float* attf = reinterpret_cast<const float*>(sm.q1);
      short* Pr = sm.q2;
      short* Pc = sm.q2 + 96 * PPS;
      const int r = tid >> 3;     // 0..95
      const int p = tid & 7;
      {   // row softmax (over y), r = x
        float av[12];
        #pragma unroll
        for (int k = 0; k < 12; ++k)
          av[k] = attf[r * AS + ((p * 12 + k) ^ (r & 31))];
        float mx = av[0];
        #pragma unroll
        for (int k = 1; k < 12; ++k) mx = fmaxf(mx, av[k]);
        mx = fmaxf(mx, __shfl_xor(mx, 1));
        mx = fmaxf(mx, __shfl_xor(mx, 2));
        mx = fmaxf(mx, __shfl_xor(mx, 4));
        float s = 0.f;
        #pragma unroll
        for (int k = 0; k < 12; ++k) { av[k] = __expf(av[k] - mx); s += av[k]; }
        s += __shfl_xor(s, 1); s += __shfl_xor(s, 2); s += __shfl_xor(s, 4);
        float inv = 1.f / s;
        #pragma unroll
        for (int k = 0; k < 12; k += 2) {
          *reinterpret_cast<unsigned*>(Pr + r * PPS + p * 12 + k) =
              pk2bf(av[k] * inv, av[k + 1] * inv);
        }
      }
      {   // column softmax (over x), r = y; write transposed
        float av[12];
        #pragma unroll
        for (int k = 0; k < 12; ++k) {
          int x = p * 12 + k;
          av[k] = attf[x * AS + (r ^ (x & 31))];
        }
        float mx = av[0];
        #pragma unroll
        for (int k = 1; k < 12; ++k) mx = fmaxf(mx, av[k]);
        mx = fmaxf(mx, __shfl_xor(mx, 1));
        mx = fmaxf(mx, __shfl_xor(mx, 2));
        mx = fmaxf(mx, __shfl_xor(mx, 4));
        float s = 0.f;
        #pragma unroll
        for (int k = 0; k < 12; ++k) { av[k] = __expf(av[k] - mx); s += av[k]; }
        s += __shfl_xor(s, 1); s += __shfl_xor(s, 2); s += __shfl_xor(s, 4);
        float inv = 1.f / s;
        #pragma unroll
        for (int k = 0; k < 12; k += 2) {
          *reinterpret_cast<unsigned*>(Pc + r * PPS + p * 12 + k) =
              pk2bf(av[k] * inv, av[k + 1] * inv);
        }
      }
    }
    __syncthreads();                                 // B5

    // W1 write: next x_l -> sm.xl ; W2 issue: next x_r loads (cover phase 7a)
    if (it < 5) {
      #pragma unroll
      for (int j = 0; j < 6; ++j) {
        int i4 = j * 768 + tid;
        int c  = i4 / 24;
        int w4 = i4 - c * 24;
        int sw = ((((c >> 3) ^ (w4 & 7)) << 3) | (c & 7));
        int base = w4 * 800 + sw;
        sm.xl[base      ] = (short)f2bf(xsl[j].x);
        sm.xl[base + 200] = (short)f2bf(xsl[j].y);
        sm.xl[base + 400] = (short)f2bf(xsl[j].z);
        sm.xl[base + 600] = (short)f2bf(xsl[j].w);
      }
      const int sbn = sliceBase + 96;
      #pragma unroll
      for (int j = 0; j < 6; ++j) {
        int i4 = j * 768 + tid;
        int c  = i4 / 24;
        int w4 = i4 - c * 24;
        xsr[j] = *reinterpret_cast<const float4*>(x_r + sbn + c * HWc + w4 * 4);
      }
    }

    // phase 7a: F_r2l via K=16 MFMA (A = vRr k-tile, B = P_row fragment),
    // D[m=c][n=x] -> packed b64 writes into q1. F_l2r accs held.
    f32x4 accL[6];
    {
      const short* Pr = sm.q2;
      const short* Pc = sm.q2 + 96 * PPS;
      const int cblk = (wid * 16 + r4) >> 3;
      const int csub = (hb & 1) * 4;
      #pragma unroll
      for (int xt = 0; xt < 6; ++xt) {
        const int x = xt * 16 + m16;
        f32x4 acc = {0.f, 0.f, 0.f, 0.f};
        #pragma unroll
        for (int kt = 0; kt < 6; ++kt) {
          bhalf4 a = __builtin_bit_cast(bhalf4, vRr[kt]);
          bhalf4 b = *reinterpret_cast<const bhalf4*>(Pr + x * PPS + kt * 16 + hb * 4);
          acc = __builtin_amdgcn_mfma_f32_16x16x16bf16_1k(a, b, acc, 0, 0, 0);
        }
        const int kx = (x >> 2) & 7;
        const int off = x * 200 + (((cblk ^ kx) << 3) | csub);
        uint2 pf;
        pf.x = pk2bf(acc[0], acc[1]);
        pf.y = pk2bf(acc[2], acc[3]);
        *reinterpret_cast<uint2*>(sm.q1 + off) = pf;   // F_r2l [x][c]
      }
      #pragma unroll
      for (int yt = 0; yt < 6; ++yt) {
        const int y = yt * 16 + m16;
        f32x4 acc = {0.f, 0.f, 0.f, 0.f};
        #pragma unroll
        for (int kt = 0; kt < 6; ++kt) {
          bhalf4 a = __builtin_bit_cast(bhalf4, vRl[kt]);
          bhalf4 b = *reinterpret_cast<const bhalf4*>(Pc + y * PPS + kt * 16 + hb * 4);
          acc = __builtin_amdgcn_mfma_f32_16x16x16bf16_1k(a, b, acc, 0, 0, 0);
        }
        accL[yt] = acc;
      }
    }
    __syncthreads();                                 // B6

    // W2 write: next x_r -> sm.xr
    if (it < 5) {
      #pragma unroll
      for (int j = 0; j < 6; ++j) {
        int i4 = j * 768 + tid;
        int c  = i4 / 24;
        int w4 = i4 - c * 24;
        int sw = ((((c >> 3) ^ (w4 & 7)) << 3) | (c & 7));
        int base = w4 * 800 + sw;
        sm.xr[base      ] = (short)f2bf(xsr[j].x);
        sm.xr[base + 200] = (short)f2bf(xsr[j].y);
        sm.xr[base + 400] = (short)f2bf(xsr[j].z);
        sm.xr[base + 600] = (short)f2bf(xsr[j].w);
      }
    }

    // phase 7b: write F_l2r over P (q2)
    {
      const int cblk = (wid * 16 + r4) >> 3;
      const int csub = (hb & 1) * 4;
      #pragma unroll
      for (int yt = 0; yt < 6; ++yt) {
        const int y = yt * 16 + m16;
        const int kx = (y >> 2) & 7;
        const int off = y * 200 + (((cblk ^ kx) << 3) | csub);
        uint2 pg;
        pg.x = pk2bf(accL[yt][0], accL[yt][1]);
        pg.y = pk2bf(accL[yt][2], accL[yt][3]);
        *reinterpret_cast<uint2*>(sm.q2 + off) = pg;   // F_l2r [y][c]
      }
    }
    __syncthreads();                                 // B7

    // phase 8: epilogue out = x + F*coef + temb (x re-read from global, L3-hot;
    // xl/xr hold NEXT slice's data by now)
    #pragma unroll
    for (int sd = 0; sd < 2; ++sd) {
      const float* xg = sd ? x_r : x_l;
      float* og = out + (sd ? HALF_OUT : 0);
      const short* Fb = sd ? sm.q2 : sm.q1;
      const float* coef = sm.misc + (sd ? 768 : 576);
      #pragma unroll
      for (int j = 0; j < 6; ++j) {
        int i4 = j * 768 + tid;
        int c  = i4 / 24;
        int w4 = i4 - c * 24;
        const float4 xv = *reinterpret_cast<const float4*>(xg + sliceBase + c * HWc + w4 * 4);
        float cf = coef[c];
        float tv = sm.misc[384 + c];
        int sw = ((((c >> 3) ^ (w4 & 7)) << 3) | (c & 7));
        int fb = w4 * 800 + sw;
        float4 ov;
        ov.x = xv.x + bf2f_s(Fb[fb      ]) * cf + tv;
        ov.y = xv.y + bf2f_s(Fb[fb + 200]) * cf + tv;
        ov.z = xv.z + bf2f_s(Fb[fb + 400]) * cf + tv;
        ov.w = xv.w + bf2f_s(Fb[fb + 600]) * cf + tv;
        *reinterpret_cast<float4*>(og + sliceBase + c * HWc + w4 * 4) = ov;
      }
    }
    __syncthreads();                                 // B8 (q1/q2/xl/xr handoff)
  }
}

// -------------------------------------------------------------------- host ---
extern "C" void kernel_launch(void* const* d_in, const int* in_sizes, int n_in,
                              void* d_out, int out_size, void* d_ws, size_t ws_size,
                              hipStream_t stream)
{
  const float* t    = (const float*)d_in[0];
  const float* x_l  = (const float*)d_in[1];
  const float* x_r  = (const float*)d_in[2];
  const float* lnwl = (const float*)d_in[3];
  const float* lnbl = (const float*)d_in[4];
  const float* lnwr = (const float*)d_in[5];
  const float* lnbr = (const float*)d_in[6];
  const float* Wl1  = (const float*)d_in[7];
  const float* bl1  = (const float*)d_in[8];
  const float* Wr1  = (const float*)d_in[9];
  const float* br1  = (const float*)d_in[10];
  const float* Wl2  = (const float*)d_in[11];
  const float* bl2  = (const float*)d_in[12];
  const float* Wr2  = (const float*)d_in[13];
  const float* br2  = (const float*)d_in[14];
  const float* beta = (const float*)d_in[15];
  const float* gamma= (const float*)d_in[16];
  const float* Wt   = (const float*)d_in[17];
  const float* bt   = (const float*)d_in[18];
  float* out = (float*)d_out;

  char* ws = (char*)d_ws;
  short* W1l_b = (short*)ws;
  short* W1r_b = W1l_b + 36864;
  short* W2l_b = W1r_b + 36864;
  short* W2r_b = W2l_b + 36864;
  float* fws  = (float*)(ws + 4 * 73728);
  float* s1l  = fws;
  float* t1l  = fws + 192;
  float* s1r  = fws + 384;
  float* t1r  = fws + 576;
  float* temb = fws + 768;   // 3072 floats
  float* mt   = fws + 3840;  // 8192 floats

  setup1<<<610, 256, 0, stream>>>(t, lnwl, lnbl, lnwr, lnbr, Wl1, bl1, Wr1, br1,
                                  Wl2, Wr2, W1l_b, W1r_b, W2l_b, W2r_b,
                                  s1l, t1l, s1r, t1r, mt);
  setup2<<<12, 256, 0, stream>>>(mt, Wt, bt, temb);
  scam_main<<<256, 768, 0, stream>>>(x_l, x_r, bl2, br2, beta, gamma,
                                     W1l_b, W1r_b, W2l_b, W2r_b,
                                     s1l, t1l, s1r, t1r, temb, out);
}

// Round 13
// 570.900 us; speedup vs baseline: 1.7138x; 1.7138x over previous
//
#include <hip/hip_runtime.h>
#include <hip/hip_bf16.h>

// SCAM fused kernel for MI355X (gfx950).
// R13 = R10 (2 WGs/CU: 80.6KB LDS, V-in-registers, K=16 PV, Q overwrites X,
// epilogue re-reads global x) + REGISTER DIET so the 85-VGPR cap of
// 6 waves/SIMD actually holds:
//  - phases 4A/4B: k-outer loop (1 weight fragment live, not 6) ->
//    peak accQ(24)+bfqk(4)+afr(4)+vR(24)+addr ~= 66 regs (was ~90+).
//  - phase 5: k-outer likewise (accA 12 + 2 transient frags).
// R10 verified the math (absmax 0.0156) and the residency (Occupancy 64%);
// its only failure was allocator collapse under the cap. This targets that.

typedef __attribute__((ext_vector_type(8))) short bhalf8;   // 8 bf16 (K=32 frag)
typedef __attribute__((ext_vector_type(4))) short bhalf4;   // 4 bf16 (K=16 frag)
typedef __attribute__((ext_vector_type(4))) float f32x4;

#define DEVI static __device__ __forceinline__

constexpr int Cc   = 192;
constexpr int HWc  = 9216;          // 96*96
constexpr int CHW  = 192 * 9216;    // per-batch image
constexpr int HALF_OUT = 16 * CHW;  // 28311552
constexpr int PPS  = 100;           // P row stride (halves)
constexpr int AS   = 100;           // att row stride (dwords)

DEVI unsigned short f2bf(float f) {           // hw cvt (RNE) via hip_bf16
  __hip_bfloat16 h = __float2bfloat16(f);
  return __builtin_bit_cast(unsigned short, h);
}
DEVI unsigned pk2bf(float a, float b) {       // packed pair: a -> low, b -> high
  return (unsigned)f2bf(a) | ((unsigned)f2bf(b) << 16);
}
DEVI float bf2f(unsigned short h) {
  unsigned u = (unsigned)h << 16;
  return __builtin_bit_cast(float, u);
}
DEVI float bf2f_s(short h) { return bf2f((unsigned short)h); }

// ---------------------------------------------------------------- setup 1 ---
__global__ void setup1(
    const float* __restrict__ t,
    const float* __restrict__ lnwl, const float* __restrict__ lnbl,
    const float* __restrict__ lnwr, const float* __restrict__ lnbr,
    const float* __restrict__ Wl1, const float* __restrict__ bl1,
    const float* __restrict__ Wr1, const float* __restrict__ br1,
    const float* __restrict__ Wl2, const float* __restrict__ Wr2,
    short* __restrict__ W1l_b, short* __restrict__ W1r_b,
    short* __restrict__ W2l_b, short* __restrict__ W2r_b,
    float* __restrict__ s1l, float* __restrict__ t1l,
    float* __restrict__ s1r, float* __restrict__ t1r,
    float* __restrict__ mt)
{
  const int blk = blockIdx.x, tid = threadIdx.x;
  if (blk < 576) {
    int id  = blk * 256 + tid;          // < 147456
    int m   = id / 36864;
    int rem = id - m * 36864;
    int c   = rem % 192;
    float v;
    short* dst;
    if (m == 0)      { v = lnwl[c] * Wl1[rem]; dst = W1l_b; }
    else if (m == 1) { v = lnwr[c] * Wr1[rem]; dst = W1r_b; }
    else if (m == 2) { v = Wl2[rem];           dst = W2l_b; }
    else             { v = Wr2[rem];           dst = W2r_b; }
    dst[rem] = (short)f2bf(v);
  } else if (blk == 576 || blk == 577) {
    if (tid < 192) {
      const float* Wm = (blk == 576) ? Wl1 : Wr1;
      const float* lw = (blk == 576) ? lnwl : lnwr;
      const float* lb = (blk == 576) ? lnbl : lnbr;
      const float* bb = (blk == 576) ? bl1 : br1;
      float s = 0.f, tb = 0.f;
      for (int c = 0; c < 192; ++c) {
        float wv = Wm[tid * 192 + c];
        s  += lw[c] * wv;
        tb += lb[c] * wv;
      }
      if (blk == 576) { s1l[tid] = s; t1l[tid] = tb + bb[tid]; }
      else            { s1r[tid] = s; t1r[tid] = tb + bb[tid]; }
    }
  } else {
    int id = (blk - 578) * 256 + tid;   // < 8192
    float v = t[id];
    float sp = (v > 20.f) ? v : log1pf(__expf(v));
    mt[id] = v * tanhf(sp);
  }
}

// temb[b][o] = sum_k mish(t)[b][k] * Wt[o][k] + bt[o]
__global__ void setup2(const float* __restrict__ mt, const float* __restrict__ Wt,
                       const float* __restrict__ bt, float* __restrict__ temb)
{
  int id = blockIdx.x * 256 + threadIdx.x;  // < 3072
  int b = id / 192, o = id - b * 192;
  float s = 0.f;
  for (int k = 0; k < 512; ++k) s += mt[b * 512 + k] * Wt[o * 512 + k];
  temb[id] = s + bt[o];
}

// ------------------------------------------------------------- main kernel ---
// misc layout (floats): 0 mu_l[96], 96 rs_l[96], 192 mu_r[96], 288 rs_r[96],
// 384 te[192], 576 beta[192], 768 gamma[192]   (end 960)
struct SmemT {
  short buf1[19200];      // X_l -> Q_l -> att(fp32 96x100dw) -> F_r2l  38400 B
  short buf2[19200];      // X_r -> Q_r -> P_row/P_colT (stride 100) -> F_l2r
  float misc[960];        //                                             3840 B
};
static_assert(sizeof(SmemT) <= 81920, "LDS overflow for 2 WGs/CU");

__launch_bounds__(768, 6)
__global__ void scam_main(
    const float* __restrict__ x_l, const float* __restrict__ x_r,
    const float* __restrict__ bl2, const float* __restrict__ br2,
    const float* __restrict__ beta, const float* __restrict__ gamma,
    const short* __restrict__ W1l_b, const short* __restrict__ W1r_b,
    const short* __restrict__ W2l_b, const short* __restrict__ W2r_b,
    const float* __restrict__ s1l, const float* __restrict__ t1l,
    const float* __restrict__ s1r, const float* __restrict__ t1r,
    const float* __restrict__ temb,
    float* __restrict__ out)
{
  __shared__ SmemT sm;
  const int tid  = threadIdx.x;
  const int lane = tid & 63;
  const int wid  = tid >> 6;            // 0..11
  const int m16  = lane & 15;
  const int hb   = lane >> 4;           // 0..3
  const int kc8  = hb * 8;              // K=32 fragment element offset
  const int r4   = hb * 4;              // D-row base
  const int slice = blockIdx.x;
  const int bb_ = slice / 96;
  const int hh_ = slice - bb_ * 96;
  const int sliceBase = bb_ * CHW + hh_ * 96;
  const int o_wm = wid * 16 + m16;

  // phase 0: small vectors into LDS (te, beta, gamma)
  if (tid < 576) {
    int a = tid / 192, o = tid - a * 192;
    if (a == 0)      sm.misc[384 + o] = temb[bb_ * 192 + o];
    else if (a == 1) sm.misc[576 + o] = beta[o];
    else             sm.misc[768 + o] = gamma[o];
  }

  // phase 1: stage x -> bf16 [w][c] rows (stride 200), coalesced global reads,
  // block-XOR LDS swizzle: element (w,c) at w*200 + ((c>>3)^((w>>2)&7))*8 + (c&7)
  #pragma unroll
  for (int j = 0; j < 6; ++j) {
    int i4 = j * 768 + tid;             // < 4608
    int c  = i4 / 24;
    int w4 = i4 - c * 24;               // w = 4*w4 + r, (w>>2)&7 = w4&7
    const float4 xl4 = *reinterpret_cast<const float4*>(x_l + sliceBase + c * HWc + w4 * 4);
    const float4 xr4 = *reinterpret_cast<const float4*>(x_r + sliceBase + c * HWc + w4 * 4);
    int sw = ((((c >> 3) ^ (w4 & 7)) << 3) | (c & 7));
    int base = w4 * 800 + sw;
    sm.buf1[base      ] = (short)f2bf(xl4.x);
    sm.buf1[base + 200] = (short)f2bf(xl4.y);
    sm.buf1[base + 400] = (short)f2bf(xl4.z);
    sm.buf1[base + 600] = (short)f2bf(xl4.w);
    sm.buf2[base      ] = (short)f2bf(xr4.x);
    sm.buf2[base + 200] = (short)f2bf(xr4.y);
    sm.buf2[base + 400] = (short)f2bf(xr4.z);
    sm.buf2[base + 600] = (short)f2bf(xr4.w);
  }
  __syncthreads();

  // phase 2: LN stats per pixel
  {
    int side = (tid >= 384) ? 1 : 0;
    int rest = tid - side * 384;
    int w = rest >> 2;
    int q = rest & 3;
    const short* Xb = side ? sm.buf2 : sm.buf1;
    const int kxw = (w >> 2) & 7;
    float s0 = 0.f, s2 = 0.f;
    #pragma unroll
    for (int mc = 0; mc < 6; ++mc) {
      bhalf8 v = *reinterpret_cast<const bhalf8*>(Xb + w * 200 + (((q * 6 + mc) ^ kxw) << 3));
      #pragma unroll
      for (int e = 0; e < 8; ++e) { float f = bf2f_s(v[e]); s0 += f; s2 += f * f; }
    }
    s0 += __shfl_xor(s0, 1); s2 += __shfl_xor(s2, 1);
    s0 += __shfl_xor(s0, 2); s2 += __shfl_xor(s2, 2);
    if (q == 0) {
      float mu  = s0 * (1.f / 192.f);
      float var = s2 * (1.f / 192.f) - mu * mu;
      float rs  = rsqrtf(var + 1e-6f);
      sm.misc[side * 192 + w]      = mu;
      sm.misc[side * 192 + 96 + w] = rs;
    }
  }

  // phase 3: V^T fragments into REGISTERS (no LDS). D[m=x][n=c]: lane holds
  // V^T[c=o_wm][y=xi*16+hb*4+j] packed bf16 -> the K=16 PV A-fragment for
  // k-tile xi. Live until phase 7. (xi-outer: af[6] + growing vR.)
  uint2 vRl[6], vRr[6];
  #pragma unroll
  for (int sd = 0; sd < 2; ++sd) {
    const short* Wb = sd ? W2r_b : W2l_b;
    const short* Xb = sd ? sm.buf2 : sm.buf1;
    const float bv = (sd ? br2 : bl2)[o_wm];
    bhalf8 af[6];
    #pragma unroll
    for (int k = 0; k < 6; ++k)
      af[k] = *reinterpret_cast<const bhalf8*>(Wb + o_wm * 192 + k * 32 + kc8);
    #pragma unroll
    for (int xi = 0; xi < 6; ++xi) {
      const int row = xi * 16 + m16;
      const int kxr = (row >> 2) & 7;
      const short* Xr = Xb + row * 200;
      f32x4 acc = {0.f, 0.f, 0.f, 0.f};
      #pragma unroll
      for (int k = 0; k < 6; ++k) {
        bhalf8 bfr = *reinterpret_cast<const bhalf8*>(Xr + (((k * 4 + hb) ^ kxr) << 3));
        acc = __builtin_amdgcn_mfma_f32_16x16x32_bf16(bfr, af[k], acc, 0, 0, 0);
      }
      uint2 pv;
      pv.x = pk2bf(acc[0] + bv, acc[1] + bv);
      pv.y = pk2bf(acc[2] + bv, acc[3] + bv);
      if (sd) vRr[xi] = pv; else vRl[xi] = pv;
    }
  }

  // phase 4A: Q_l accs (reads X_l), D[m=o][n=x]. K-OUTER: one weight
  // fragment live at a time -> peak regs ~66, fits the 85 cap.
  f32x4 accQ[6];
  #pragma unroll
  for (int mi = 0; mi < 6; ++mi) accQ[mi] = f32x4{0.f, 0.f, 0.f, 0.f};
  #pragma unroll
  for (int k = 0; k < 6; ++k) {
    bhalf8 bfqk = *reinterpret_cast<const bhalf8*>(W1l_b + o_wm * 192 + k * 32 + kc8);
    #pragma unroll
    for (int mi = 0; mi < 6; ++mi) {
      const int row = mi * 16 + m16;
      const int kxr = (row >> 2) & 7;
      bhalf8 afr = *reinterpret_cast<const bhalf8*>(sm.buf1 + row * 200 + (((k * 4 + hb) ^ kxr) << 3));
      accQ[mi] = __builtin_amdgcn_mfma_f32_16x16x32_bf16(bfqk, afr, accQ[mi], 0, 0, 0);
    }
  }
  __syncthreads();   // LN misc ready; all buf1 reads done
  // write Q_l over X_l (buf1): Q = rs*acc - mu*rs*s1[o] + t1[o]
  {
    const int obase = wid * 16 + r4;
    const int oblk  = obase >> 3;
    const int osub  = (hb & 1) * 4;
    const float* muA = sm.misc;
    const float* rsA = sm.misc + 96;
    float s1v[4], t1v[4];
    #pragma unroll
    for (int j = 0; j < 4; ++j) { s1v[j] = s1l[obase + j]; t1v[j] = t1l[obase + j]; }
    #pragma unroll
    for (int mi = 0; mi < 6; ++mi) {
      const int x = mi * 16 + m16;
      const int kx = (x >> 2) & 7;
      float mu = muA[x], rs = rsA[x];
      float mrs = mu * rs;
      f32x4 acc = accQ[mi];
      uint2 pv;
      pv.x = pk2bf(rs * acc[0] - mrs * s1v[0] + t1v[0],
                   rs * acc[1] - mrs * s1v[1] + t1v[1]);
      pv.y = pk2bf(rs * acc[2] - mrs * s1v[2] + t1v[2],
                   rs * acc[3] - mrs * s1v[3] + t1v[3]);
      *reinterpret_cast<uint2*>(sm.buf1 + x * 200 + (((oblk ^ kx) << 3) | osub)) = pv;
    }
  }
  // phase 4B: Q_r accs (reads X_r, untouched). K-outer again.
  #pragma unroll
  for (int mi = 0; mi < 6; ++mi) accQ[mi] = f32x4{0.f, 0.f, 0.f, 0.f};
  #pragma unroll
  for (int k = 0; k < 6; ++k) {
    bhalf8 bfqk = *reinterpret_cast<const bhalf8*>(W1r_b + o_wm * 192 + k * 32 + kc8);
    #pragma unroll
    for (int mi = 0; mi < 6; ++mi) {
      const int row = mi * 16 + m16;
      const int kxr = (row >> 2) & 7;
      bhalf8 afr = *reinterpret_cast<const bhalf8*>(sm.buf2 + row * 200 + (((k * 4 + hb) ^ kxr) << 3));
      accQ[mi] = __builtin_amdgcn_mfma_f32_16x16x32_bf16(bfqk, afr, accQ[mi], 0, 0, 0);
    }
  }
  __syncthreads();   // all buf2 reads done
  // write Q_r over X_r (buf2)
  {
    const int obase = wid * 16 + r4;
    const int oblk  = obase >> 3;
    const int osub  = (hb & 1) * 4;
    const float* muA = sm.misc + 192;
    const float* rsA = sm.misc + 288;
    float s1v[4], t1v[4];
    #pragma unroll
    for (int j = 0; j < 4; ++j) { s1v[j] = s1r[obase + j]; t1v[j] = t1r[obase + j]; }
    #pragma unroll
    for (int mi = 0; mi < 6; ++mi) {
      const int x = mi * 16 + m16;
      const int kx = (x >> 2) & 7;
      float mu = muA[x], rs = rsA[x];
      float mrs = mu * rs;
      f32x4 acc = accQ[mi];
      uint2 pv;
      pv.x = pk2bf(rs * acc[0] - mrs * s1v[0] + t1v[0],
                   rs * acc[1] - mrs * s1v[1] + t1v[1]);
      pv.y = pk2bf(rs * acc[2] - mrs * s1v[2] + t1v[2],
                   rs * acc[3] - mrs * s1v[3] + t1v[3]);
      *reinterpret_cast<uint2*>(sm.buf2 + x * 200 + (((oblk ^ kx) << 3) | osub)) = pv;
    }
  }
  __syncthreads();

  // phase 5: att = Q_l * Q_r^T (scaled) -> fp32 over buf1 (stride 100 dw),
  // column swizzle y ^ (x&31). K-OUTER (accA 12 + 2 transient frags).
  {
    const int mi = wid >> 1;
    const int yb = (wid & 1) * 3;
    const int arow = mi * 16 + m16;
    const int kxa = (arow >> 2) & 7;
    f32x4 accA[3];
    #pragma unroll
    for (int yt = 0; yt < 3; ++yt) accA[yt] = f32x4{0.f, 0.f, 0.f, 0.f};
    #pragma unroll
    for (int k = 0; k < 6; ++k) {
      bhalf8 afa = *reinterpret_cast<const bhalf8*>(sm.buf1 + arow * 200 + (((k * 4 + hb) ^ kxa) << 3));
      #pragma unroll
      for (int yt = 0; yt < 3; ++yt) {
        const int brow = (yb + yt) * 16 + m16;
        const int kxb = (brow >> 2) & 7;
        bhalf8 bfy = *reinterpret_cast<const bhalf8*>(sm.buf2 + brow * 200 + (((k * 4 + hb) ^ kxb) << 3));
        accA[yt] = __builtin_amdgcn_mfma_f32_16x16x32_bf16(afa, bfy, accA[yt], 0, 0, 0);
      }
    }
    __syncthreads();
    float* attf = reinterpret_cast<float*>(sm.buf1);
    const float scale = 0.07216878364870323f;   // 192^-0.5
    #pragma unroll
    for (int yt = 0; yt < 3; ++yt) {
      #pragma unroll
      for (int j = 0; j < 4; ++j) {
        int x = mi * 16 + r4 + j;
        int y = (yb + yt) * 16 + m16;
        attf[x * AS + (y ^ (x & 31))] = accA[yt][j] * scale;
      }
    }
  }
  __syncthreads();

  // phase 6: dual softmax -> P_row (bf16 [x][y], stride 100), P_colT ([y][x])
  {
    const float* attf = reinterpret_cast<const float*>(sm.buf1);
    short* Pr = sm.buf2;
    short* Pc = sm.buf2 + 96 * PPS;
    const int r = tid >> 3;     // 0..95
    const int p = tid & 7;
    {   // row softmax (over y), r = x
      float av[12];
      #pragma unroll
      for (int k = 0; k < 12; ++k)
        av[k] = attf[r * AS + ((p * 12 + k) ^ (r & 31))];
      float mx = av[0];
      #pragma unroll
      for (int k = 1; k < 12; ++k) mx = fmaxf(mx, av[k]);
      mx = fmaxf(mx, __shfl_xor(mx, 1));
      mx = fmaxf(mx, __shfl_xor(mx, 2));
      mx = fmaxf(mx, __shfl_xor(mx, 4));
      float s = 0.f;
      #pragma unroll
      for (int k = 0; k < 12; ++k) { av[k] = __expf(av[k] - mx); s += av[k]; }
      s += __shfl_xor(s, 1); s += __shfl_xor(s, 2); s += __shfl_xor(s, 4);
      float inv = 1.f / s;
      #pragma unroll
      for (int k = 0; k < 12; k += 2) {
        *reinterpret_cast<unsigned*>(Pr + r * PPS + p * 12 + k) =
            pk2bf(av[k] * inv, av[k + 1] * inv);
      }
    }
    {   // column softmax (over x), r = y; write transposed
      float av[12];
      #pragma unroll
      for (int k = 0; k < 12; ++k) {
        int x = p * 12 + k;
        av[k] = attf[x * AS + (r ^ (x & 31))];
      }
      float mx = av[0];
      #pragma unroll
      for (int k = 1; k < 12; ++k) mx = fmaxf(mx, av[k]);
      mx = fmaxf(mx, __shfl_xor(mx, 1));
      mx = fmaxf(mx, __shfl_xor(mx, 2));
      mx = fmaxf(mx, __shfl_xor(mx, 4));
      float s = 0.f;
      #pragma unroll
      for (int k = 0; k < 12; ++k) { av[k] = __expf(av[k] - mx); s += av[k]; }
      s += __shfl_xor(s, 1); s += __shfl_xor(s, 2); s += __shfl_xor(s, 4);
      float inv = 1.f / s;
      #pragma unroll
      for (int k = 0; k < 12; k += 2) {
        *reinterpret_cast<unsigned*>(Pc + r * PPS + p * 12 + k) =
            pk2bf(av[k] * inv, av[k + 1] * inv);
      }
    }
  }
  __syncthreads();

  // phase 7a: F_r2l via K=16 MFMA (A = vRr k-tile, B = P_row fragment),
  // D[m=c][n=x] -> packed b64 writes into buf1 (att dead). F_l2r accs held.
  f32x4 accL[6];
  {
    const short* Pr = sm.buf2;
    const short* Pc = sm.buf2 + 96 * PPS;
    const int cblk = (wid * 16 + r4) >> 3;
    const int csub = (hb & 1) * 4;
    #pragma unroll
    for (int xt = 0; xt < 6; ++xt) {
      const int x = xt * 16 + m16;
      f32x4 acc = {0.f, 0.f, 0.f, 0.f};
      #pragma unroll
      for (int kt = 0; kt < 6; ++kt) {
        bhalf4 a = __builtin_bit_cast(bhalf4, vRr[kt]);
        bhalf4 b = *reinterpret_cast<const bhalf4*>(Pr + x * PPS + kt * 16 + hb * 4);
        acc = __builtin_amdgcn_mfma_f32_16x16x16bf16_1k(a, b, acc, 0, 0, 0);
      }
      const int kx = (x >> 2) & 7;
      const int off = x * 200 + (((cblk ^ kx) << 3) | csub);
      uint2 pf;
      pf.x = pk2bf(acc[0], acc[1]);
      pf.y = pk2bf(acc[2], acc[3]);
      *reinterpret_cast<uint2*>(sm.buf1 + off) = pf;     // F_r2l [x][c]
    }
    #pragma unroll
    for (int yt = 0; yt < 6; ++yt) {
      const int y = yt * 16 + m16;
      f32x4 acc = {0.f, 0.f, 0.f, 0.f};
      #pragma unroll
      for (int kt = 0; kt < 6; ++kt) {
        bhalf4 a = __builtin_bit_cast(bhalf4, vRl[kt]);
        bhalf4 b = *reinterpret_cast<const bhalf4*>(Pc + y * PPS + kt * 16 + hb * 4);
        acc = __builtin_amdgcn_mfma_f32_16x16x16bf16_1k(a, b, acc, 0, 0, 0);
      }
      accL[yt] = acc;
    }
  }
  __syncthreads();
  // phase 7b: write F_l2r over P (buf2)
  {
    const int cblk = (wid * 16 + r4) >> 3;
    const int csub = (hb & 1) * 4;
    #pragma unroll
    for (int yt = 0; yt < 6; ++yt) {
      const int y = yt * 16 + m16;
      const int kx = (y >> 2) & 7;
      const int off = y * 200 + (((cblk ^ kx) << 3) | csub);
      uint2 pg;
      pg.x = pk2bf(accL[yt][0], accL[yt][1]);
      pg.y = pk2bf(accL[yt][2], accL[yt][3]);
      *reinterpret_cast<uint2*>(sm.buf2 + off) = pg;     // F_l2r [y][c]
    }
  }
  __syncthreads();

  // phase 8: epilogue  out = x + F*coef + temb  (coalesced; x re-read L2/L3-hot)
  #pragma unroll
  for (int sd = 0; sd < 2; ++sd) {
    const float* xg = sd ? x_r : x_l;
    float* og = out + (sd ? HALF_OUT : 0);
    const short* Fb = sd ? sm.buf2 : sm.buf1;
    const float* coef = sm.misc + (sd ? 768 : 576);
    #pragma unroll
    for (int j = 0; j < 6; ++j) {
      int i4 = j * 768 + tid;
      int c  = i4 / 24;
      int w4 = i4 - c * 24;
      const float4 xv = *reinterpret_cast<const float4*>(xg + sliceBase + c * HWc + w4 * 4);
      float cf = coef[c];
      float tv = sm.misc[384 + c];
      int sw = ((((c >> 3) ^ (w4 & 7)) << 3) | (c & 7));
      int fb = w4 * 800 + sw;
      float4 ov;
      ov.x = xv.x + bf2f_s(Fb[fb      ]) * cf + tv;
      ov.y = xv.y + bf2f_s(Fb[fb + 200]) * cf + tv;
      ov.z = xv.z + bf2f_s(Fb[fb + 400]) * cf + tv;
      ov.w = xv.w + bf2f_s(Fb[fb + 600]) * cf + tv;
      *reinterpret_cast<float4*>(og + sliceBase + c * HWc + w4 * 4) = ov;
    }
  }
}

// -------------------------------------------------------------------- host ---
extern "C" void kernel_launch(void* const* d_in, const int* in_sizes, int n_in,
                              void* d_out, int out_size, void* d_ws, size_t ws_size,
                              hipStream_t stream)
{
  const float* t    = (const float*)d_in[0];
  const float* x_l  = (const float*)d_in[1];
  const float* x_r  = (const float*)d_in[2];
  const float* lnwl = (const float*)d_in[3];
  const float* lnbl = (const float*)d_in[4];
  const float* lnwr = (const float*)d_in[5];
  const float* lnbr = (const float*)d_in[6];
  const float* Wl1  = (const float*)d_in[7];
  const float* bl1  = (const float*)d_in[8];
  const float* Wr1  = (const float*)d_in[9];
  const float* br1  = (const float*)d_in[10];
  const float* Wl2  = (const float*)d_in[11];
  const float* bl2  = (const float*)d_in[12];
  const float* Wr2  = (const float*)d_in[13];
  const float* br2  = (const float*)d_in[14];
  const float* beta = (const float*)d_in[15];
  const float* gamma= (const float*)d_in[16];
  const float* Wt   = (const float*)d_in[17];
  const float* bt   = (const float*)d_in[18];
  float* out = (float*)d_out;

  char* ws = (char*)d_ws;
  short* W1l_b = (short*)ws;
  short* W1r_b = W1l_b + 36864;
  short* W2l_b = W1r_b + 36864;
  short* W2r_b = W2l_b + 36864;
  float* fws  = (float*)(ws + 4 * 73728);
  float* s1l  = fws;
  float* t1l  = fws + 192;
  float* s1r  = fws + 384;
  float* t1r  = fws + 576;
  float* temb = fws + 768;   // 3072 floats
  float* mt   = fws + 3840;  // 8192 floats

  setup1<<<610, 256, 0, stream>>>(t, lnwl, lnbl, lnwr, lnbr, Wl1, bl1, Wr1, br1,
                                  Wl2, Wr2, W1l_b, W1r_b, W2l_b, W2r_b,
                                  s1l, t1l, s1r, t1r, mt);
  setup2<<<12, 256, 0, stream>>>(mt, Wt, bt, temb);
  scam_main<<<1536, 768, 0, stream>>>(x_l, x_r, bl2, br2, beta, gamma,
                                      W1l_b, W1r_b, W2l_b, W2r_b,
                                      s1l, t1l, s1r, t1r, temb, out);
}

// Round 14
// 514.736 us; speedup vs baseline: 1.9008x; 1.1091x over previous
//
#include <hip/hip_runtime.h>
#include <hip/hip_bf16.h>

// SCAM fused kernel for MI355X (gfx950).
// R14: 2 WGs/CU with INDEPENDENT barrier domains, at full register budget.
// 384 threads/WG (6 waves) x 2 WGs = 12 waves/CU = 3 waves/SIMD -> 170-reg
// cap (same as R11), unlike the failed 768-thr 2-WG attempts (85-reg cap,
// spilled: R10/R13). LDS 80.6KB/WG x2 = 161.3KB. Each wave owns 2 of the 12
// c/o-tiles; V stays in registers (vR[2][6]); K=16 PV; Q overwrites X;
// epilogue re-reads global x (L3-hot). WG-A's memory phases overlap WG-B's
// compute via the CU scheduler - the overlap software pipelining failed to get.

typedef __attribute__((ext_vector_type(8))) short bhalf8;   // 8 bf16 (K=32 frag)
typedef __attribute__((ext_vector_type(4))) short bhalf4;   // 4 bf16 (K=16 frag)
typedef __attribute__((ext_vector_type(4))) float f32x4;

#define DEVI static __device__ __forceinline__

constexpr int Cc   = 192;
constexpr int HWc  = 9216;          // 96*96
constexpr int CHW  = 192 * 9216;    // per-batch image
constexpr int HALF_OUT = 16 * CHW;  // 28311552
constexpr int PPS  = 100;           // P row stride (halves)
constexpr int AS   = 100;           // att row stride (dwords)

DEVI unsigned short f2bf(float f) {           // hw cvt (RNE) via hip_bf16
  __hip_bfloat16 h = __float2bfloat16(f);
  return __builtin_bit_cast(unsigned short, h);
}
DEVI unsigned pk2bf(float a, float b) {       // packed pair: a -> low, b -> high
  return (unsigned)f2bf(a) | ((unsigned)f2bf(b) << 16);
}
DEVI float bf2f(unsigned short h) {
  unsigned u = (unsigned)h << 16;
  return __builtin_bit_cast(float, u);
}
DEVI float bf2f_s(short h) { return bf2f((unsigned short)h); }

// ---------------------------------------------------------------- setup 1 ---
__global__ void setup1(
    const float* __restrict__ t,
    const float* __restrict__ lnwl, const float* __restrict__ lnbl,
    const float* __restrict__ lnwr, const float* __restrict__ lnbr,
    const float* __restrict__ Wl1, const float* __restrict__ bl1,
    const float* __restrict__ Wr1, const float* __restrict__ br1,
    const float* __restrict__ Wl2, const float* __restrict__ Wr2,
    short* __restrict__ W1l_b, short* __restrict__ W1r_b,
    short* __restrict__ W2l_b, short* __restrict__ W2r_b,
    float* __restrict__ s1l, float* __restrict__ t1l,
    float* __restrict__ s1r, float* __restrict__ t1r,
    float* __restrict__ mt)
{
  const int blk = blockIdx.x, tid = threadIdx.x;
  if (blk < 576) {
    int id  = blk * 256 + tid;          // < 147456
    int m   = id / 36864;
    int rem = id - m * 36864;
    int c   = rem % 192;
    float v;
    short* dst;
    if (m == 0)      { v = lnwl[c] * Wl1[rem]; dst = W1l_b; }
    else if (m == 1) { v = lnwr[c] * Wr1[rem]; dst = W1r_b; }
    else if (m == 2) { v = Wl2[rem];           dst = W2l_b; }
    else             { v = Wr2[rem];           dst = W2r_b; }
    dst[rem] = (short)f2bf(v);
  } else if (blk == 576 || blk == 577) {
    if (tid < 192) {
      const float* Wm = (blk == 576) ? Wl1 : Wr1;
      const float* lw = (blk == 576) ? lnwl : lnwr;
      const float* lb = (blk == 576) ? lnbl : lnbr;
      const float* bb = (blk == 576) ? bl1 : br1;
      float s = 0.f, tb = 0.f;
      for (int c = 0; c < 192; ++c) {
        float wv = Wm[tid * 192 + c];
        s  += lw[c] * wv;
        tb += lb[c] * wv;
      }
      if (blk == 576) { s1l[tid] = s; t1l[tid] = tb + bb[tid]; }
      else            { s1r[tid] = s; t1r[tid] = tb + bb[tid]; }
    }
  } else {
    int id = (blk - 578) * 256 + tid;   // < 8192
    float v = t[id];
    float sp = (v > 20.f) ? v : log1pf(__expf(v));
    mt[id] = v * tanhf(sp);
  }
}

// temb[b][o] = sum_k mish(t)[b][k] * Wt[o][k] + bt[o]
__global__ void setup2(const float* __restrict__ mt, const float* __restrict__ Wt,
                       const float* __restrict__ bt, float* __restrict__ temb)
{
  int id = blockIdx.x * 256 + threadIdx.x;  // < 3072
  int b = id / 192, o = id - b * 192;
  float s = 0.f;
  for (int k = 0; k < 512; ++k) s += mt[b * 512 + k] * Wt[o * 512 + k];
  temb[id] = s + bt[o];
}

// ------------------------------------------------------------- main kernel ---
// misc layout (floats): 0 mu_l[96], 96 rs_l[96], 192 mu_r[96], 288 rs_r[96],
// 384 te[192], 576 beta[192], 768 gamma[192]   (end 960)
struct SmemT {
  short buf1[19200];      // X_l -> Q_l -> att(fp32 96x100dw) -> F_r2l  38400 B
  short buf2[19200];      // X_r -> Q_r -> P_row/P_colT (stride 100) -> F_l2r
  float misc[960];        //                                             3840 B
};
static_assert(sizeof(SmemT) <= 81920, "LDS overflow for 2 WGs/CU");

__launch_bounds__(384, 3)
__global__ void scam_main(
    const float* __restrict__ x_l, const float* __restrict__ x_r,
    const float* __restrict__ bl2, const float* __restrict__ br2,
    const float* __restrict__ beta, const float* __restrict__ gamma,
    const short* __restrict__ W1l_b, const short* __restrict__ W1r_b,
    const short* __restrict__ W2l_b, const short* __restrict__ W2r_b,
    const float* __restrict__ s1l, const float* __restrict__ t1l,
    const float* __restrict__ s1r, const float* __restrict__ t1r,
    const float* __restrict__ temb,
    float* __restrict__ out)
{
  __shared__ SmemT sm;
  const int tid  = threadIdx.x;         // 0..383
  const int lane = tid & 63;
  const int wid  = tid >> 6;            // 0..5
  const int m16  = lane & 15;
  const int hb   = lane >> 4;           // 0..3
  const int kc8  = hb * 8;              // K=32 fragment element offset
  const int r4   = hb * 4;              // D-row base
  const int slice = blockIdx.x;
  const int bb_ = slice / 96;
  const int hh_ = slice - bb_ * 96;
  const int sliceBase = bb_ * CHW + hh_ * 96;

  // phase 0: small vectors into LDS (te, beta, gamma)
  for (int idx = tid; idx < 576; idx += 384) {
    int a = idx / 192, o = idx - a * 192;
    if (a == 0)      sm.misc[384 + o] = temb[bb_ * 192 + o];
    else if (a == 1) sm.misc[576 + o] = beta[o];
    else             sm.misc[768 + o] = gamma[o];
  }

  // phase 1: stage x -> bf16 [w][c] rows (stride 200), coalesced global reads,
  // block-XOR LDS swizzle: element (w,c) at w*200 + ((c>>3)^((w>>2)&7))*8 + (c&7)
  #pragma unroll
  for (int j = 0; j < 12; ++j) {
    int i4 = j * 384 + tid;             // < 4608
    int c  = i4 / 24;
    int w4 = i4 - c * 24;               // w = 4*w4 + r, (w>>2)&7 = w4&7
    const float4 xl4 = *reinterpret_cast<const float4*>(x_l + sliceBase + c * HWc + w4 * 4);
    const float4 xr4 = *reinterpret_cast<const float4*>(x_r + sliceBase + c * HWc + w4 * 4);
    int sw = ((((c >> 3) ^ (w4 & 7)) << 3) | (c & 7));
    int base = w4 * 800 + sw;
    sm.buf1[base      ] = (short)f2bf(xl4.x);
    sm.buf1[base + 200] = (short)f2bf(xl4.y);
    sm.buf1[base + 400] = (short)f2bf(xl4.z);
    sm.buf1[base + 600] = (short)f2bf(xl4.w);
    sm.buf2[base      ] = (short)f2bf(xr4.x);
    sm.buf2[base + 200] = (short)f2bf(xr4.y);
    sm.buf2[base + 400] = (short)f2bf(xr4.z);
    sm.buf2[base + 600] = (short)f2bf(xr4.w);
  }
  __syncthreads();

  // phase 2: LN stats per pixel. 384 thr = 2 sides x 96 rows x 2 (q);
  // each thread sums 96 channels (12 bhalf8 blocks), pair-reduce via shfl.
  {
    int side = (tid >= 192) ? 1 : 0;
    int rest = tid - side * 192;
    int w = rest >> 1;
    int q = rest & 1;
    const short* Xb = side ? sm.buf2 : sm.buf1;
    const int kxw = (w >> 2) & 7;
    float s0 = 0.f, s2 = 0.f;
    #pragma unroll
    for (int mc = 0; mc < 12; ++mc) {
      bhalf8 v = *reinterpret_cast<const bhalf8*>(Xb + w * 200 + (((q * 12 + mc) ^ kxw) << 3));
      #pragma unroll
      for (int e = 0; e < 8; ++e) { float f = bf2f_s(v[e]); s0 += f; s2 += f * f; }
    }
    s0 += __shfl_xor(s0, 1); s2 += __shfl_xor(s2, 1);
    if (q == 0) {
      float mu  = s0 * (1.f / 192.f);
      float var = s2 * (1.f / 192.f) - mu * mu;
      float rs  = rsqrtf(var + 1e-6f);
      sm.misc[side * 192 + w]      = mu;
      sm.misc[side * 192 + 96 + w] = rs;
    }
  }

  // phase 3: V^T fragments into registers. Each wave owns c-tiles {wid, wid+6}.
  // D[m=x][n=c]: lane holds V^T[c=(wid+6h)*16+m16][y=xi*16+hb*4+j] = the K=16
  // PV A-fragment for k-tile xi. vR[2][6] lives until phase 7.
  uint2 vRl[2][6], vRr[2][6];
  #pragma unroll
  for (int sd = 0; sd < 2; ++sd) {
    const short* Wb = sd ? W2r_b : W2l_b;
    const short* Xb = sd ? sm.buf2 : sm.buf1;
    float bv[2];
    bhalf8 af[2][6];
    #pragma unroll
    for (int h = 0; h < 2; ++h) {
      const int c0 = (wid + 6 * h) * 16 + m16;
      bv[h] = (sd ? br2 : bl2)[c0];
      #pragma unroll
      for (int k = 0; k < 6; ++k)
        af[h][k] = *reinterpret_cast<const bhalf8*>(Wb + c0 * 192 + k * 32 + kc8);
    }
    #pragma unroll
    for (int xi = 0; xi < 6; ++xi) {
      const int row = xi * 16 + m16;
      const int kxr = (row >> 2) & 7;
      const short* Xr = Xb + row * 200;
      f32x4 a0 = {0.f, 0.f, 0.f, 0.f}, a1 = {0.f, 0.f, 0.f, 0.f};
      #pragma unroll
      for (int k = 0; k < 6; ++k) {
        bhalf8 bfr = *reinterpret_cast<const bhalf8*>(Xr + (((k * 4 + hb) ^ kxr) << 3));
        a0 = __builtin_amdgcn_mfma_f32_16x16x32_bf16(bfr, af[0][k], a0, 0, 0, 0);
        a1 = __builtin_amdgcn_mfma_f32_16x16x32_bf16(bfr, af[1][k], a1, 0, 0, 0);
      }
      uint2 p0, p1;
      p0.x = pk2bf(a0[0] + bv[0], a0[1] + bv[0]);
      p0.y = pk2bf(a0[2] + bv[0], a0[3] + bv[0]);
      p1.x = pk2bf(a1[0] + bv[1], a1[1] + bv[1]);
      p1.y = pk2bf(a1[2] + bv[1], a1[3] + bv[1]);
      if (sd) { vRr[0][xi] = p0; vRr[1][xi] = p1; }
      else    { vRl[0][xi] = p0; vRl[1][xi] = p1; }
    }
  }

  // phase 4A: Q_l accs (reads X_l), D[m=o][n=x]; o-tiles {wid, wid+6}.
  // K-outer; X fragment shared by both o-tiles.
  f32x4 accQ[2][6];
  #pragma unroll
  for (int h = 0; h < 2; ++h)
    #pragma unroll
    for (int mi = 0; mi < 6; ++mi) accQ[h][mi] = f32x4{0.f, 0.f, 0.f, 0.f};
  #pragma unroll
  for (int k = 0; k < 6; ++k) {
    bhalf8 bq0 = *reinterpret_cast<const bhalf8*>(W1l_b + ((wid    ) * 16 + m16) * 192 + k * 32 + kc8);
    bhalf8 bq1 = *reinterpret_cast<const bhalf8*>(W1l_b + ((wid + 6) * 16 + m16) * 192 + k * 32 + kc8);
    #pragma unroll
    for (int mi = 0; mi < 6; ++mi) {
      const int row = mi * 16 + m16;
      const int kxr = (row >> 2) & 7;
      bhalf8 afr = *reinterpret_cast<const bhalf8*>(sm.buf1 + row * 200 + (((k * 4 + hb) ^ kxr) << 3));
      accQ[0][mi] = __builtin_amdgcn_mfma_f32_16x16x32_bf16(bq0, afr, accQ[0][mi], 0, 0, 0);
      accQ[1][mi] = __builtin_amdgcn_mfma_f32_16x16x32_bf16(bq1, afr, accQ[1][mi], 0, 0, 0);
    }
  }
  __syncthreads();   // LN misc ready; all buf1 X reads done
  // write Q_l over X_l (buf1): Q = rs*acc - mu*rs*s1[o] + t1[o]
  #pragma unroll
  for (int h = 0; h < 2; ++h) {
    const int obase = (wid + 6 * h) * 16 + r4;
    const int oblk  = obase >> 3;
    const int osub  = (hb & 1) * 4;
    const float* muA = sm.misc;
    const float* rsA = sm.misc + 96;
    float s1v[4], t1v[4];
    #pragma unroll
    for (int j = 0; j < 4; ++j) { s1v[j] = s1l[obase + j]; t1v[j] = t1l[obase + j]; }
    #pragma unroll
    for (int mi = 0; mi < 6; ++mi) {
      const int x = mi * 16 + m16;
      const int kx = (x >> 2) & 7;
      float mu = muA[x], rs = rsA[x];
      float mrs = mu * rs;
      f32x4 acc = accQ[h][mi];
      uint2 pv;
      pv.x = pk2bf(rs * acc[0] - mrs * s1v[0] + t1v[0],
                   rs * acc[1] - mrs * s1v[1] + t1v[1]);
      pv.y = pk2bf(rs * acc[2] - mrs * s1v[2] + t1v[2],
                   rs * acc[3] - mrs * s1v[3] + t1v[3]);
      *reinterpret_cast<uint2*>(sm.buf1 + x * 200 + (((oblk ^ kx) << 3) | osub)) = pv;
    }
  }
  // phase 4B: Q_r accs (reads X_r, untouched). Same scheme.
  #pragma unroll
  for (int h = 0; h < 2; ++h)
    #pragma unroll
    for (int mi = 0; mi < 6; ++mi) accQ[h][mi] = f32x4{0.f, 0.f, 0.f, 0.f};
  #pragma unroll
  for (int k = 0; k < 6; ++k) {
    bhalf8 bq0 = *reinterpret_cast<const bhalf8*>(W1r_b + ((wid    ) * 16 + m16) * 192 + k * 32 + kc8);
    bhalf8 bq1 = *reinterpret_cast<const bhalf8*>(W1r_b + ((wid + 6) * 16 + m16) * 192 + k * 32 + kc8);
    #pragma unroll
    for (int mi = 0; mi < 6; ++mi) {
      const int row = mi * 16 + m16;
      const int kxr = (row >> 2) & 7;
      bhalf8 afr = *reinterpret_cast<const bhalf8*>(sm.buf2 + row * 200 + (((k * 4 + hb) ^ kxr) << 3));
      accQ[0][mi] = __builtin_amdgcn_mfma_f32_16x16x32_bf16(bq0, afr, accQ[0][mi], 0, 0, 0);
      accQ[1][mi] = __builtin_amdgcn_mfma_f32_16x16x32_bf16(bq1, afr, accQ[1][mi], 0, 0, 0);
    }
  }
  __syncthreads();   // all buf2 X reads done
  // write Q_r over X_r (buf2)
  #pragma unroll
  for (int h = 0; h < 2; ++h) {
    const int obase = (wid + 6 * h) * 16 + r4;
    const int oblk  = obase >> 3;
    const int osub  = (hb & 1) * 4;
    const float* muA = sm.misc + 192;
    const float* rsA = sm.misc + 288;
    float s1v[4], t1v[4];
    #pragma unroll
    for (int j = 0; j < 4; ++j) { s1v[j] = s1r[obase + j]; t1v[j] = t1r[obase + j]; }
    #pragma unroll
    for (int mi = 0; mi < 6; ++mi) {
      const int x = mi * 16 + m16;
      const int kx = (x >> 2) & 7;
      float mu = muA[x], rs = rsA[x];
      float mrs = mu * rs;
      f32x4 acc = accQ[h][mi];
      uint2 pv;
      pv.x = pk2bf(rs * acc[0] - mrs * s1v[0] + t1v[0],
                   rs * acc[1] - mrs * s1v[1] + t1v[1]);
      pv.y = pk2bf(rs * acc[2] - mrs * s1v[2] + t1v[2],
                   rs * acc[3] - mrs * s1v[3] + t1v[3]);
      *reinterpret_cast<uint2*>(sm.buf2 + x * 200 + (((oblk ^ kx) << 3) | osub)) = pv;
    }
  }
  __syncthreads();

  // phase 5: att = Q_l * Q_r^T (scaled) -> fp32 over buf1, swizzle y^(x&31).
  // Each wave owns x-tile wid, all 6 y-tiles. K-outer, accA[6].
  {
    const int arow = wid * 16 + m16;
    const int kxa = (arow >> 2) & 7;
    f32x4 accA[6];
    #pragma unroll
    for (int yt = 0; yt < 6; ++yt) accA[yt] = f32x4{0.f, 0.f, 0.f, 0.f};
    #pragma unroll
    for (int k = 0; k < 6; ++k) {
      bhalf8 afa = *reinterpret_cast<const bhalf8*>(sm.buf1 + arow * 200 + (((k * 4 + hb) ^ kxa) << 3));
      #pragma unroll
      for (int yt = 0; yt < 6; ++yt) {
        const int brow = yt * 16 + m16;
        const int kxb = (brow >> 2) & 7;
        bhalf8 bfy = *reinterpret_cast<const bhalf8*>(sm.buf2 + brow * 200 + (((k * 4 + hb) ^ kxb) << 3));
        accA[yt] = __builtin_amdgcn_mfma_f32_16x16x32_bf16(afa, bfy, accA[yt], 0, 0, 0);
      }
    }
    __syncthreads();
    float* attf = reinterpret_cast<float*>(sm.buf1);
    const float scale = 0.07216878364870323f;   // 192^-0.5
    #pragma unroll
    for (int yt = 0; yt < 6; ++yt) {
      #pragma unroll
      for (int j = 0; j < 4; ++j) {
        int x = wid * 16 + r4 + j;
        int y = yt * 16 + m16;
        attf[x * AS + (y ^ (x & 31))] = accA[yt][j] * scale;
      }
    }
  }
  __syncthreads();

  // phase 6: dual softmax -> P_row (bf16 [x][y], stride 100), P_colT ([y][x]).
  // 384 thr: 4 threads/row, 24 elems each.
  {
    const float* attf = reinterpret_cast<const float*>(sm.buf1);
    short* Pr = sm.buf2;
    short* Pc = sm.buf2 + 96 * PPS;
    const int r = tid >> 2;     // 0..95
    const int p = tid & 3;
    {   // row softmax (over y), r = x
      float av[24];
      #pragma unroll
      for (int k = 0; k < 24; ++k)
        av[k] = attf[r * AS + ((p * 24 + k) ^ (r & 31))];
      float mx = av[0];
      #pragma unroll
      for (int k = 1; k < 24; ++k) mx = fmaxf(mx, av[k]);
      mx = fmaxf(mx, __shfl_xor(mx, 1));
      mx = fmaxf(mx, __shfl_xor(mx, 2));
      float s = 0.f;
      #pragma unroll
      for (int k = 0; k < 24; ++k) { av[k] = __expf(av[k] - mx); s += av[k]; }
      s += __shfl_xor(s, 1); s += __shfl_xor(s, 2);
      float inv = 1.f / s;
      #pragma unroll
      for (int k = 0; k < 24; k += 2) {
        *reinterpret_cast<unsigned*>(Pr + r * PPS + p * 24 + k) =
            pk2bf(av[k] * inv, av[k + 1] * inv);
      }
    }
    {   // column softmax (over x), r = y; write transposed
      float av[24];
      #pragma unroll
      for (int k = 0; k < 24; ++k) {
        int x = p * 24 + k;
        av[k] = attf[x * AS + (r ^ (x & 31))];
      }
      float mx = av[0];
      #pragma unroll
      for (int k = 1; k < 24; ++k) mx = fmaxf(mx, av[k]);
      mx = fmaxf(mx, __shfl_xor(mx, 1));
      mx = fmaxf(mx, __shfl_xor(mx, 2));
      float s = 0.f;
      #pragma unroll
      for (int k = 0; k < 24; ++k) { av[k] = __expf(av[k] - mx); s += av[k]; }
      s += __shfl_xor(s, 1); s += __shfl_xor(s, 2);
      float inv = 1.f / s;
      #pragma unroll
      for (int k = 0; k < 24; k += 2) {
        *reinterpret_cast<unsigned*>(Pc + r * PPS + p * 24 + k) =
            pk2bf(av[k] * inv, av[k + 1] * inv);
      }
    }
  }
  __syncthreads();

  // phase 7a: F_r2l via K=16 MFMA (A = vRr[h][kt], B = P_row fragment),
  // D[m=c (tile wid+6h)][n=x] -> packed b64 writes into buf1 (att dead).
  // F_l2r accs held in accL[2][6].
  f32x4 accL[2][6];
  {
    const short* Pr = sm.buf2;
    const short* Pc = sm.buf2 + 96 * PPS;
    const int csub = (hb & 1) * 4;
    #pragma unroll
    for (int xt = 0; xt < 6; ++xt) {
      const int x = xt * 16 + m16;
      f32x4 a0 = {0.f, 0.f, 0.f, 0.f}, a1 = {0.f, 0.f, 0.f, 0.f};
      #pragma unroll
      for (int kt = 0; kt < 6; ++kt) {
        bhalf4 b = *reinterpret_cast<const bhalf4*>(Pr + x * PPS + kt * 16 + hb * 4);
        a0 = __builtin_amdgcn_mfma_f32_16x16x16bf16_1k(__builtin_bit_cast(bhalf4, vRr[0][kt]), b, a0, 0, 0, 0);
        a1 = __builtin_amdgcn_mfma_f32_16x16x16bf16_1k(__builtin_bit_cast(bhalf4, vRr[1][kt]), b, a1, 0, 0, 0);
      }
      const int kx = (x >> 2) & 7;
      #pragma unroll
      for (int h = 0; h < 2; ++h) {
        const int cblk = ((wid + 6 * h) * 16 + r4) >> 3;
        const int off = x * 200 + (((cblk ^ kx) << 3) | csub);
        uint2 pf;
        f32x4 a = h ? a1 : a0;
        pf.x = pk2bf(a[0], a[1]);
        pf.y = pk2bf(a[2], a[3]);
        *reinterpret_cast<uint2*>(sm.buf1 + off) = pf;   // F_r2l [x][c]
      }
    }
    #pragma unroll
    for (int yt = 0; yt < 6; ++yt) {
      const int y = yt * 16 + m16;
      f32x4 a0 = {0.f, 0.f, 0.f, 0.f}, a1 = {0.f, 0.f, 0.f, 0.f};
      #pragma unroll
      for (int kt = 0; kt < 6; ++kt) {
        bhalf4 b = *reinterpret_cast<const bhalf4*>(Pc + y * PPS + kt * 16 + hb * 4);
        a0 = __builtin_amdgcn_mfma_f32_16x16x16bf16_1k(__builtin_bit_cast(bhalf4, vRl[0][kt]), b, a0, 0, 0, 0);
        a1 = __builtin_amdgcn_mfma_f32_16x16x16bf16_1k(__builtin_bit_cast(bhalf4, vRl[1][kt]), b, a1, 0, 0, 0);
      }
      accL[0][yt] = a0;
      accL[1][yt] = a1;
    }
  }
  __syncthreads();
  // phase 7b: write F_l2r over P (buf2)
  {
    const int csub = (hb & 1) * 4;
    #pragma unroll
    for (int yt = 0; yt < 6; ++yt) {
      const int y = yt * 16 + m16;
      const int kx = (y >> 2) & 7;
      #pragma unroll
      for (int h = 0; h < 2; ++h) {
        const int cblk = ((wid + 6 * h) * 16 + r4) >> 3;
        const int off = y * 200 + (((cblk ^ kx) << 3) | csub);
        uint2 pg;
        f32x4 a = accL[h][yt];
        pg.x = pk2bf(a[0], a[1]);
        pg.y = pk2bf(a[2], a[3]);
        *reinterpret_cast<uint2*>(sm.buf2 + off) = pg;   // F_l2r [y][c]
      }
    }
  }
  __syncthreads();

  // phase 8: epilogue  out = x + F*coef + temb  (coalesced; x re-read L2/L3-hot)
  #pragma unroll
  for (int sd = 0; sd < 2; ++sd) {
    const float* xg = sd ? x_r : x_l;
    float* og = out + (sd ? HALF_OUT : 0);
    const short* Fb = sd ? sm.buf2 : sm.buf1;
    const float* coef = sm.misc + (sd ? 768 : 576);
    #pragma unroll
    for (int j = 0; j < 12; ++j) {
      int i4 = j * 384 + tid;
      int c  = i4 / 24;
      int w4 = i4 - c * 24;
      const float4 xv = *reinterpret_cast<const float4*>(xg + sliceBase + c * HWc + w4 * 4);
      float cf = coef[c];
      float tv = sm.misc[384 + c];
      int sw = ((((c >> 3) ^ (w4 & 7)) << 3) | (c & 7));
      int fb = w4 * 800 + sw;
      float4 ov;
      ov.x = xv.x + bf2f_s(Fb[fb      ]) * cf + tv;
      ov.y = xv.y + bf2f_s(Fb[fb + 200]) * cf + tv;
      ov.z = xv.z + bf2f_s(Fb[fb + 400]) * cf + tv;
      ov.w = xv.w + bf2f_s(Fb[fb + 600]) * cf + tv;
      *reinterpret_cast<float4*>(og + sliceBase + c * HWc + w4 * 4) = ov;
    }
  }
}

// -------------------------------------------------------------------- host ---
extern "C" void kernel_launch(void* const* d_in, const int* in_sizes, int n_in,
                              void* d_out, int out_size, void* d_ws, size_t ws_size,
                              hipStream_t stream)
{
  const float* t    = (const float*)d_in[0];
  const float* x_l  = (const float*)d_in[1];
  const float* x_r  = (const float*)d_in[2];
  const float* lnwl = (const float*)d_in[3];
  const float* lnbl = (const float*)d_in[4];
  const float* lnwr = (const float*)d_in[5];
  const float* lnbr = (const float*)d_in[6];
  const float* Wl1  = (const float*)d_in[7];
  const float* bl1  = (const float*)d_in[8];
  const float* Wr1  = (const float*)d_in[9];
  const float* br1  = (const float*)d_in[10];
  const float* Wl2  = (const float*)d_in[11];
  const float* bl2  = (const float*)d_in[12];
  const float* Wr2  = (const float*)d_in[13];
  const float* br2  = (const float*)d_in[14];
  const float* beta = (const float*)d_in[15];
  const float* gamma= (const float*)d_in[16];
  const float* Wt   = (const float*)d_in[17];
  const float* bt   = (const float*)d_in[18];
  float* out = (float*)d_out;

  char* ws = (char*)d_ws;
  short* W1l_b = (short*)ws;
  short* W1r_b = W1l_b + 36864;
  short* W2l_b = W1r_b + 36864;
  short* W2r_b = W2l_b + 36864;
  float* fws  = (float*)(ws + 4 * 73728);
  float* s1l  = fws;
  float* t1l  = fws + 192;
  float* s1r  = fws + 384;
  float* t1r  = fws + 576;
  float* temb = fws + 768;   // 3072 floats
  float* mt   = fws + 3840;  // 8192 floats

  setup1<<<610, 256, 0, stream>>>(t, lnwl, lnbl, lnwr, lnbr, Wl1, bl1, Wr1, br1,
                                  Wl2, Wr2, W1l_b, W1r_b, W2l_b, W2r_b,
                                  s1l, t1l, s1r, t1r, mt);
  setup2<<<12, 256, 0, stream>>>(mt, Wt, bt, temb);
  scam_main<<<1536, 384, 0, stream>>>(x_l, x_r, bl2, br2, beta, gamma,
                                      W1l_b, W1r_b, W2l_b, W2r_b,
                                      s1l, t1l, s1r, t1r, temb, out);
}

// Round 15
// 254.330 us; speedup vs baseline: 3.8470x; 2.0239x over previous
//
#include <hip/hip_runtime.h>
#include <hip/hip_bf16.h>

// SCAM fused kernel for MI355X (gfx950).
// R15 = R11 verbatim (measured best: 249.7 us, VGPR 84, no scratch).
//  - One WG per (b,h) slice, 768 threads, 1 WG/CU (157.4 KB LDS).
//  - V never touches LDS: phase-3 D[m=x][n=c] fragment IS the K=16 PV
//    A-operand (mfma_f32_16x16x16bf16_1k).
//  - X_l/X_r stay resident in LDS all kernel; Q gets its own buffers;
//    epilogue reads x from LDS (no global reads after staging).
//  - Phase 4 split by side (24 acc held, not 48). launch_bounds(768,3).
// Residual uses bf16(x) (absmax ~0.031, threshold 0.116).

typedef __attribute__((ext_vector_type(8))) short bhalf8;   // 8 bf16 (K=32 frag)
typedef __attribute__((ext_vector_type(4))) short bhalf4;   // 4 bf16 (K=16 frag)
typedef __attribute__((ext_vector_type(4))) float f32x4;

#define DEVI static __device__ __forceinline__

constexpr int Cc   = 192;
constexpr int HWc  = 9216;          // 96*96
constexpr int CHW  = 192 * 9216;    // per-batch image
constexpr int HALF_OUT = 16 * CHW;  // 28311552
constexpr int PPS  = 100;           // P row stride (halves)
constexpr int AS   = 100;           // att row stride (dwords)

DEVI unsigned short f2bf(float f) {           // hw cvt (RNE) via hip_bf16
  __hip_bfloat16 h = __float2bfloat16(f);
  return __builtin_bit_cast(unsigned short, h);
}
DEVI unsigned pk2bf(float a, float b) {       // packed pair: a -> low, b -> high
  return (unsigned)f2bf(a) | ((unsigned)f2bf(b) << 16);
}
DEVI float bf2f(unsigned short h) {
  unsigned u = (unsigned)h << 16;
  return __builtin_bit_cast(float, u);
}
DEVI float bf2f_s(short h) { return bf2f((unsigned short)h); }

// ---------------------------------------------------------------- setup 1 ---
__global__ void setup1(
    const float* __restrict__ t,
    const float* __restrict__ lnwl, const float* __restrict__ lnbl,
    const float* __restrict__ lnwr, const float* __restrict__ lnbr,
    const float* __restrict__ Wl1, const float* __restrict__ bl1,
    const float* __restrict__ Wr1, const float* __restrict__ br1,
    const float* __restrict__ Wl2, const float* __restrict__ Wr2,
    short* __restrict__ W1l_b, short* __restrict__ W1r_b,
    short* __restrict__ W2l_b, short* __restrict__ W2r_b,
    float* __restrict__ s1l, float* __restrict__ t1l,
    float* __restrict__ s1r, float* __restrict__ t1r,
    float* __restrict__ mt)
{
  const int blk = blockIdx.x, tid = threadIdx.x;
  if (blk < 576) {
    int id  = blk * 256 + tid;          // < 147456
    int m   = id / 36864;
    int rem = id - m * 36864;
    int c   = rem % 192;
    float v;
    short* dst;
    if (m == 0)      { v = lnwl[c] * Wl1[rem]; dst = W1l_b; }
    else if (m == 1) { v = lnwr[c] * Wr1[rem]; dst = W1r_b; }
    else if (m == 2) { v = Wl2[rem];           dst = W2l_b; }
    else             { v = Wr2[rem];           dst = W2r_b; }
    dst[rem] = (short)f2bf(v);
  } else if (blk == 576 || blk == 577) {
    if (tid < 192) {
      const float* Wm = (blk == 576) ? Wl1 : Wr1;
      const float* lw = (blk == 576) ? lnwl : lnwr;
      const float* lb = (blk == 576) ? lnbl : lnbr;
      const float* bb = (blk == 576) ? bl1 : br1;
      float s = 0.f, tb = 0.f;
      for (int c = 0; c < 192; ++c) {
        float wv = Wm[tid * 192 + c];
        s  += lw[c] * wv;
        tb += lb[c] * wv;
      }
      if (blk == 576) { s1l[tid] = s; t1l[tid] = tb + bb[tid]; }
      else            { s1r[tid] = s; t1r[tid] = tb + bb[tid]; }
    }
  } else {
    int id = (blk - 578) * 256 + tid;   // < 8192
    float v = t[id];
    float sp = (v > 20.f) ? v : log1pf(__expf(v));
    mt[id] = v * tanhf(sp);
  }
}

// temb[b][o] = sum_k mish(t)[b][k] * Wt[o][k] + bt[o]
__global__ void setup2(const float* __restrict__ mt, const float* __restrict__ Wt,
                       const float* __restrict__ bt, float* __restrict__ temb)
{
  int id = blockIdx.x * 256 + threadIdx.x;  // < 3072
  int b = id / 192, o = id - b * 192;
  float s = 0.f;
  for (int k = 0; k < 512; ++k) s += mt[b * 512 + k] * Wt[o * 512 + k];
  temb[id] = s + bt[o];
}

// ------------------------------------------------------------- main kernel ---
// misc layout (floats): 0 mu_l[96], 96 rs_l[96], 192 mu_r[96], 288 rs_r[96],
// 384 te[192], 576 beta[192], 768 gamma[192]   (end 960)
struct SmemT {
  short xl[19200];   // X_l bf16 swizzled [w][c] stride 200 — live all kernel
  short xr[19200];   // X_r
  short q1[19200];   // Q_l -> att (fp32 96x100dw) -> F_r2l
  short q2[19200];   // Q_r -> P_row/P_colT (stride 100)  -> F_l2r
  float misc[960];
};
static_assert(sizeof(SmemT) <= 163840, "LDS overflow");

__launch_bounds__(768, 3)
__global__ void scam_main(
    const float* __restrict__ x_l, const float* __restrict__ x_r,
    const float* __restrict__ bl2, const float* __restrict__ br2,
    const float* __restrict__ beta, const float* __restrict__ gamma,
    const short* __restrict__ W1l_b, const short* __restrict__ W1r_b,
    const short* __restrict__ W2l_b, const short* __restrict__ W2r_b,
    const float* __restrict__ s1l, const float* __restrict__ t1l,
    const float* __restrict__ s1r, const float* __restrict__ t1r,
    const float* __restrict__ temb,
    float* __restrict__ out)
{
  __shared__ SmemT sm;
  const int tid  = threadIdx.x;
  const int lane = tid & 63;
  const int wid  = tid >> 6;            // 0..11
  const int m16  = lane & 15;
  const int hb   = lane >> 4;           // 0..3
  const int kc8  = hb * 8;              // K=32 fragment element offset
  const int r4   = hb * 4;              // D-row base
  const int slice = blockIdx.x;
  const int bb_ = slice / 96;
  const int hh_ = slice - bb_ * 96;
  const int sliceBase = bb_ * CHW + hh_ * 96;
  const int o_wm = wid * 16 + m16;

  // phase 0: small vectors into LDS (te, beta, gamma)
  if (tid < 576) {
    int a = tid / 192, o = tid - a * 192;
    if (a == 0)      sm.misc[384 + o] = temb[bb_ * 192 + o];
    else if (a == 1) sm.misc[576 + o] = beta[o];
    else             sm.misc[768 + o] = gamma[o];
  }

  // phase 1: stage x -> bf16 [w][c] rows (stride 200), coalesced global reads,
  // block-XOR LDS swizzle: element (w,c) at w*200 + ((c>>3)^((w>>2)&7))*8 + (c&7)
  #pragma unroll
  for (int j = 0; j < 6; ++j) {
    int i4 = j * 768 + tid;             // < 4608
    int c  = i4 / 24;
    int w4 = i4 - c * 24;               // w = 4*w4 + r, (w>>2)&7 = w4&7
    const float4 xl4 = *reinterpret_cast<const float4*>(x_l + sliceBase + c * HWc + w4 * 4);
    const float4 xr4 = *reinterpret_cast<const float4*>(x_r + sliceBase + c * HWc + w4 * 4);
    int sw = ((((c >> 3) ^ (w4 & 7)) << 3) | (c & 7));
    int base = w4 * 800 + sw;
    sm.xl[base      ] = (short)f2bf(xl4.x);
    sm.xl[base + 200] = (short)f2bf(xl4.y);
    sm.xl[base + 400] = (short)f2bf(xl4.z);
    sm.xl[base + 600] = (short)f2bf(xl4.w);
    sm.xr[base      ] = (short)f2bf(xr4.x);
    sm.xr[base + 200] = (short)f2bf(xr4.y);
    sm.xr[base + 400] = (short)f2bf(xr4.z);
    sm.xr[base + 600] = (short)f2bf(xr4.w);
  }
  __syncthreads();

  // phase 2: LN stats per pixel (writes misc mu/rs)
  {
    int side = (tid >= 384) ? 1 : 0;
    int rest = tid - side * 384;
    int w = rest >> 2;
    int q = rest & 3;
    const short* Xb = side ? sm.xr : sm.xl;
    const int kxw = (w >> 2) & 7;
    float s0 = 0.f, s2 = 0.f;
    #pragma unroll
    for (int mc = 0; mc < 6; ++mc) {
      bhalf8 v = *reinterpret_cast<const bhalf8*>(Xb + w * 200 + (((q * 6 + mc) ^ kxw) << 3));
      #pragma unroll
      for (int e = 0; e < 8; ++e) { float f = bf2f_s(v[e]); s0 += f; s2 += f * f; }
    }
    s0 += __shfl_xor(s0, 1); s2 += __shfl_xor(s2, 1);
    s0 += __shfl_xor(s0, 2); s2 += __shfl_xor(s2, 2);
    if (q == 0) {
      float mu  = s0 * (1.f / 192.f);
      float var = s2 * (1.f / 192.f) - mu * mu;
      float rs  = rsqrtf(var + 1e-6f);
      sm.misc[side * 192 + w]      = mu;
      sm.misc[side * 192 + 96 + w] = rs;
    }
  }

  // phase 3: V^T fragments into REGISTERS (no LDS traffic). D[m=x][n=c]:
  // lane holds V^T[c=o_wm][y=xi*16+hb*4+j] packed bf16 — exactly the K=16
  // A-fragment for PV k-tile xi. Live until phase 7.
  uint2 vRl[6], vRr[6];
  #pragma unroll
  for (int sd = 0; sd < 2; ++sd) {
    const short* Wb = sd ? W2r_b : W2l_b;
    const short* Xb = sd ? sm.xr : sm.xl;
    const float bv = (sd ? br2 : bl2)[o_wm];
    bhalf8 af[6];
    #pragma unroll
    for (int k = 0; k < 6; ++k)
      af[k] = *reinterpret_cast<const bhalf8*>(Wb + o_wm * 192 + k * 32 + kc8);
    #pragma unroll
    for (int xi = 0; xi < 6; ++xi) {
      const int row = xi * 16 + m16;
      const int kxr = (row >> 2) & 7;
      const short* Xr = Xb + row * 200;
      f32x4 acc = {0.f, 0.f, 0.f, 0.f};
      #pragma unroll
      for (int k = 0; k < 6; ++k) {
        bhalf8 bfr = *reinterpret_cast<const bhalf8*>(Xr + (((k * 4 + hb) ^ kxr) << 3));
        acc = __builtin_amdgcn_mfma_f32_16x16x32_bf16(bfr, af[k], acc, 0, 0, 0);
      }
      uint2 pv;
      pv.x = pk2bf(acc[0] + bv, acc[1] + bv);
      pv.y = pk2bf(acc[2] + bv, acc[3] + bv);
      if (sd) vRr[xi] = pv; else vRl[xi] = pv;
    }
  }

  // phase 4A: Q_l accs (reads X_l), D[m=o][n=x]
  f32x4 accQ[6];
  {
    bhalf8 bfq[6];
    #pragma unroll
    for (int k = 0; k < 6; ++k)
      bfq[k] = *reinterpret_cast<const bhalf8*>(W1l_b + o_wm * 192 + k * 32 + kc8);
    #pragma unroll
    for (int mi = 0; mi < 6; ++mi) {
      const int row = mi * 16 + m16;
      const int kxr = (row >> 2) & 7;
      const short* Xr = sm.xl + row * 200;
      f32x4 acc = {0.f, 0.f, 0.f, 0.f};
      #pragma unroll
      for (int k = 0; k < 6; ++k) {
        bhalf8 afr = *reinterpret_cast<const bhalf8*>(Xr + (((k * 4 + hb) ^ kxr) << 3));
        acc = __builtin_amdgcn_mfma_f32_16x16x32_bf16(bfq[k], afr, acc, 0, 0, 0);
      }
      accQ[mi] = acc;
    }
  }
  __syncthreads();   // LN misc ready (Q writes below read mu/rs)
  // write Q_l -> q1 (own buffer; X untouched): Q = rs*acc - mu*rs*s1 + t1
  {
    const int obase = wid * 16 + r4;
    const int oblk  = obase >> 3;
    const int osub  = (hb & 1) * 4;
    const float* muA = sm.misc;
    const float* rsA = sm.misc + 96;
    float s1v[4], t1v[4];
    #pragma unroll
    for (int j = 0; j < 4; ++j) { s1v[j] = s1l[obase + j]; t1v[j] = t1l[obase + j]; }
    #pragma unroll
    for (int mi = 0; mi < 6; ++mi) {
      const int x = mi * 16 + m16;
      const int kx = (x >> 2) & 7;
      float mu = muA[x], rs = rsA[x];
      float mrs = mu * rs;
      f32x4 acc = accQ[mi];
      uint2 pv;
      pv.x = pk2bf(rs * acc[0] - mrs * s1v[0] + t1v[0],
                   rs * acc[1] - mrs * s1v[1] + t1v[1]);
      pv.y = pk2bf(rs * acc[2] - mrs * s1v[2] + t1v[2],
                   rs * acc[3] - mrs * s1v[3] + t1v[3]);
      *reinterpret_cast<uint2*>(sm.q1 + x * 200 + (((oblk ^ kx) << 3) | osub)) = pv;
    }
  }
  // phase 4B: Q_r accs (reads X_r) then write -> q2
  {
    bhalf8 bfq[6];
    #pragma unroll
    for (int k = 0; k < 6; ++k)
      bfq[k] = *reinterpret_cast<const bhalf8*>(W1r_b + o_wm * 192 + k * 32 + kc8);
    #pragma unroll
    for (int mi = 0; mi < 6; ++mi) {
      const int row = mi * 16 + m16;
      const int kxr = (row >> 2) & 7;
      const short* Xr = sm.xr + row * 200;
      f32x4 acc = {0.f, 0.f, 0.f, 0.f};
      #pragma unroll
      for (int k = 0; k < 6; ++k) {
        bhalf8 afr = *reinterpret_cast<const bhalf8*>(Xr + (((k * 4 + hb) ^ kxr) << 3));
        acc = __builtin_amdgcn_mfma_f32_16x16x32_bf16(bfq[k], afr, acc, 0, 0, 0);
      }
      accQ[mi] = acc;
    }
  }
  {
    const int obase = wid * 16 + r4;
    const int oblk  = obase >> 3;
    const int osub  = (hb & 1) * 4;
    const float* muA = sm.misc + 192;
    const float* rsA = sm.misc + 288;
    float s1v[4], t1v[4];
    #pragma unroll
    for (int j = 0; j < 4; ++j) { s1v[j] = s1r[obase + j]; t1v[j] = t1r[obase + j]; }
    #pragma unroll
    for (int mi = 0; mi < 6; ++mi) {
      const int x = mi * 16 + m16;
      const int kx = (x >> 2) & 7;
      float mu = muA[x], rs = rsA[x];
      float mrs = mu * rs;
      f32x4 acc = accQ[mi];
      uint2 pv;
      pv.x = pk2bf(rs * acc[0] - mrs * s1v[0] + t1v[0],
                   rs * acc[1] - mrs * s1v[1] + t1v[1]);
      pv.y = pk2bf(rs * acc[2] - mrs * s1v[2] + t1v[2],
                   rs * acc[3] - mrs * s1v[3] + t1v[3]);
      *reinterpret_cast<uint2*>(sm.q2 + x * 200 + (((oblk ^ kx) << 3) | osub)) = pv;
    }
  }
  __syncthreads();

  // phase 5: att = Q_l * Q_r^T (scaled) -> fp32 over q1 (stride 100 dw),
  // column swizzle y ^ (x&31)
  {
    const int mi = wid >> 1;
    const int yb = (wid & 1) * 3;
    const int arow = mi * 16 + m16;
    const int kxa = (arow >> 2) & 7;
    bhalf8 afa[6];
    #pragma unroll
    for (int k = 0; k < 6; ++k)
      afa[k] = *reinterpret_cast<const bhalf8*>(sm.q1 + arow * 200 + (((k * 4 + hb) ^ kxa) << 3));
    f32x4 accA[3];
    #pragma unroll
    for (int yt = 0; yt < 3; ++yt) {
      const int brow = (yb + yt) * 16 + m16;
      const int kxb = (brow >> 2) & 7;
      const short* Br = sm.q2 + brow * 200;
      f32x4 acc = {0.f, 0.f, 0.f, 0.f};
      #pragma unroll
      for (int k = 0; k < 6; ++k) {
        bhalf8 bfy = *reinterpret_cast<const bhalf8*>(Br + (((k * 4 + hb) ^ kxb) << 3));
        acc = __builtin_amdgcn_mfma_f32_16x16x32_bf16(afa[k], bfy, acc, 0, 0, 0);
      }
      accA[yt] = acc;
    }
    __syncthreads();
    float* attf = reinterpret_cast<float*>(sm.q1);
    const float scale = 0.07216878364870323f;   // 192^-0.5
    #pragma unroll
    for (int yt = 0; yt < 3; ++yt) {
      #pragma unroll
      for (int j = 0; j < 4; ++j) {
        int x = mi * 16 + r4 + j;
        int y = (yb + yt) * 16 + m16;
        attf[x * AS + (y ^ (x & 31))] = accA[yt][j] * scale;
      }
    }
  }
  __syncthreads();

  // phase 6: dual softmax -> P_row (bf16 [x][y], stride 100), P_colT ([y][x]) in q2
  {
    const float* attf = reinterpret_cast<const float*>(sm.q1);
    short* Pr = sm.q2;
    short* Pc = sm.q2 + 96 * PPS;
    const int r = tid >> 3;     // 0..95
    const int p = tid & 7;
    {   // row softmax (over y), r = x
      float av[12];
      #pragma unroll
      for (int k = 0; k < 12; ++k)
        av[k] = attf[r * AS + ((p * 12 + k) ^ (r & 31))];
      float mx = av[0];
      #pragma unroll
      for (int k = 1; k < 12; ++k) mx = fmaxf(mx, av[k]);
      mx = fmaxf(mx, __shfl_xor(mx, 1));
      mx = fmaxf(mx, __shfl_xor(mx, 2));
      mx = fmaxf(mx, __shfl_xor(mx, 4));
      float s = 0.f;
      #pragma unroll
      for (int k = 0; k < 12; ++k) { av[k] = __expf(av[k] - mx); s += av[k]; }
      s += __shfl_xor(s, 1); s += __shfl_xor(s, 2); s += __shfl_xor(s, 4);
      float inv = 1.f / s;
      #pragma unroll
      for (int k = 0; k < 12; k += 2) {
        *reinterpret_cast<unsigned*>(Pr + r * PPS + p * 12 + k) =
            pk2bf(av[k] * inv, av[k + 1] * inv);
      }
    }
    {   // column softmax (over x), r = y; write transposed
      float av[12];
      #pragma unroll
      for (int k = 0; k < 12; ++k) {
        int x = p * 12 + k;
        av[k] = attf[x * AS + (r ^ (x & 31))];
      }
      float mx = av[0];
      #pragma unroll
      for (int k = 1; k < 12; ++k) mx = fmaxf(mx, av[k]);
      mx = fmaxf(mx, __shfl_xor(mx, 1));
      mx = fmaxf(mx, __shfl_xor(mx, 2));
      mx = fmaxf(mx, __shfl_xor(mx, 4));
      float s = 0.f;
      #pragma unroll
      for (int k = 0; k < 12; ++k) { av[k] = __expf(av[k] - mx); s += av[k]; }
      s += __shfl_xor(s, 1); s += __shfl_xor(s, 2); s += __shfl_xor(s, 4);
      float inv = 1.f / s;
      #pragma unroll
      for (int k = 0; k < 12; k += 2) {
        *reinterpret_cast<unsigned*>(Pc + r * PPS + p * 12 + k) =
            pk2bf(av[k] * inv, av[k + 1] * inv);
      }
    }
  }
  __syncthreads();

  // phase 7a: F_r2l via K=16 MFMA (A = vRr k-tile, B = P_row fragment),
  // D[m=c][n=x] -> packed b64 writes into q1 (att dead). F_l2r accs held.
  f32x4 accL[6];
  {
    const short* Pr = sm.q2;
    const short* Pc = sm.q2 + 96 * PPS;
    const int cblk = (wid * 16 + r4) >> 3;
    const int csub = (hb & 1) * 4;
    #pragma unroll
    for (int xt = 0; xt < 6; ++xt) {
      const int x = xt * 16 + m16;
      f32x4 acc = {0.f, 0.f, 0.f, 0.f};
      #pragma unroll
      for (int kt = 0; kt < 6; ++kt) {
        bhalf4 a = __builtin_bit_cast(bhalf4, vRr[kt]);
        bhalf4 b = *reinterpret_cast<const bhalf4*>(Pr + x * PPS + kt * 16 + hb * 4);
        acc = __builtin_amdgcn_mfma_f32_16x16x16bf16_1k(a, b, acc, 0, 0, 0);
      }
      const int kx = (x >> 2) & 7;
      const int off = x * 200 + (((cblk ^ kx) << 3) | csub);
      uint2 pf;
      pf.x = pk2bf(acc[0], acc[1]);
      pf.y = pk2bf(acc[2], acc[3]);
      *reinterpret_cast<uint2*>(sm.q1 + off) = pf;       // F_r2l [x][c]
    }
    #pragma unroll
    for (int yt = 0; yt < 6; ++yt) {
      const int y = yt * 16 + m16;
      f32x4 acc = {0.f, 0.f, 0.f, 0.f};
      #pragma unroll
      for (int kt = 0; kt < 6; ++kt) {
        bhalf4 a = __builtin_bit_cast(bhalf4, vRl[kt]);
        bhalf4 b = *reinterpret_cast<const bhalf4*>(Pc + y * PPS + kt * 16 + hb * 4);
        acc = __builtin_amdgcn_mfma_f32_16x16x16bf16_1k(a, b, acc, 0, 0, 0);
      }
      accL[yt] = acc;
    }
  }
  __syncthreads();
  // phase 7b: write F_l2r over P (q2)
  {
    const int cblk = (wid * 16 + r4) >> 3;
    const int csub = (hb & 1) * 4;
    #pragma unroll
    for (int yt = 0; yt < 6; ++yt) {
      const int y = yt * 16 + m16;
      const int kx = (y >> 2) & 7;
      const int off = y * 200 + (((cblk ^ kx) << 3) | csub);
      uint2 pg;
      pg.x = pk2bf(accL[yt][0], accL[yt][1]);
      pg.y = pk2bf(accL[yt][2], accL[yt][3]);
      *reinterpret_cast<uint2*>(sm.q2 + off) = pg;       // F_l2r [y][c]
    }
  }
  __syncthreads();

  // phase 8: epilogue  out = bf16(x) + F*coef + temb — NO global reads:
  // x comes from the resident LDS copy; stores fully coalesced.
  #pragma unroll
  for (int sd = 0; sd < 2; ++sd) {
    float* og = out + (sd ? HALF_OUT : 0);
    const short* Fb = sd ? sm.q2 : sm.q1;
    const short* Xb = sd ? sm.xr : sm.xl;
    const float* coef = sm.misc + (sd ? 768 : 576);
    #pragma unroll
    for (int j = 0; j < 6; ++j) {
      int i4 = j * 768 + tid;
      int c  = i4 / 24;
      int w4 = i4 - c * 24;
      float cf = coef[c];
      float tv = sm.misc[384 + c];
      int sw = ((((c >> 3) ^ (w4 & 7)) << 3) | (c & 7));
      int fb = w4 * 800 + sw;
      float4 ov;
      ov.x = bf2f_s(Xb[fb      ]) + bf2f_s(Fb[fb      ]) * cf + tv;
      ov.y = bf2f_s(Xb[fb + 200]) + bf2f_s(Fb[fb + 200]) * cf + tv;
      ov.z = bf2f_s(Xb[fb + 400]) + bf2f_s(Fb[fb + 400]) * cf + tv;
      ov.w = bf2f_s(Xb[fb + 600]) + bf2f_s(Fb[fb + 600]) * cf + tv;
      *reinterpret_cast<float4*>(og + sliceBase + c * HWc + w4 * 4) = ov;
    }
  }
}

// -------------------------------------------------------------------- host ---
extern "C" void kernel_launch(void* const* d_in, const int* in_sizes, int n_in,
                              void* d_out, int out_size, void* d_ws, size_t ws_size,
                              hipStream_t stream)
{
  const float* t    = (const float*)d_in[0];
  const float* x_l  = (const float*)d_in[1];
  const float* x_r  = (const float*)d_in[2];
  const float* lnwl = (const float*)d_in[3];
  const float* lnbl = (const float*)d_in[4];
  const float* lnwr = (const float*)d_in[5];
  const float* lnbr = (const float*)d_in[6];
  const float* Wl1  = (const float*)d_in[7];
  const float* bl1  = (const float*)d_in[8];
  const float* Wr1  = (const float*)d_in[9];
  const float* br1  = (const float*)d_in[10];
  const float* Wl2  = (const float*)d_in[11];
  const float* bl2  = (const float*)d_in[12];
  const float* Wr2  = (const float*)d_in[13];
  const float* br2  = (const float*)d_in[14];
  const float* beta = (const float*)d_in[15];
  const float* gamma= (const float*)d_in[16];
  const float* Wt   = (const float*)d_in[17];
  const float* bt   = (const float*)d_in[18];
  float* out = (float*)d_out;

  char* ws = (char*)d_ws;
  short* W1l_b = (short*)ws;
  short* W1r_b = W1l_b + 36864;
  short* W2l_b = W1r_b + 36864;
  short* W2r_b = W2l_b + 36864;
  float* fws  = (float*)(ws + 4 * 73728);
  float* s1l  = fws;
  float* t1l  = fws + 192;
  float* s1r  = fws + 384;
  float* t1r  = fws + 576;
  float* temb = fws + 768;   // 3072 floats
  float* mt   = fws + 3840;  // 8192 floats

  setup1<<<610, 256, 0, stream>>>(t, lnwl, lnbl, lnwr, lnbr, Wl1, bl1, Wr1, br1,
                                  Wl2, Wr2, W1l_b, W1r_b, W2l_b, W2r_b,
                                  s1l, t1l, s1r, t1r, mt);
  setup2<<<12, 256, 0, stream>>>(mt, Wt, bt, temb);
  scam_main<<<1536, 768, 0, stream>>>(x_l, x_r, bl2, br2, beta, gamma,
                                      W1l_b, W1r_b, W2l_b, W2r_b,
                                      s1l, t1l, s1r, t1r, temb, out);
}